// Round 1
// baseline (160.068 us; speedup 1.0000x reference)
//
#include <hip/hip_runtime.h>

// Problem constants (from reference config)
#define FD 56          // depth samples: linspace(2, 58, 56)
#define FH 112         // 900 / 8
#define FW 200         // 1600 / 8
#define VD 16          // volume D
#define VH 200         // volume H
#define VW 200         // volume W
#define NC 32          // channels
#define NPIX (FH * FW)         // 22400
#define NS   (VD * VH * VW)    // 640000 spatial voxels
#define CSTRIDE NS             // floats per channel (channel-major input)

typedef float f2v __attribute__((ext_vector_type(2)));
typedef f2v uf2v4 __attribute__((aligned(4)));   // fallback: 8B vec, 4B-align safe
typedef _Float16 h4 __attribute__((ext_vector_type(4)));
typedef h4 uh4 __attribute__((aligned(8)));
typedef _Float16 h8 __attribute__((ext_vector_type(8)));

// Compute fused projection matrix M = e2f @ T @ [[K^-1,0],[0,1]] (12 floats,
// rows = (W,H,D) feature coords). Device helper, runs on one thread.
__device__ inline void compute_M(const float* Km, const float* Tm, float* M) {
    float a = Km[0], b = Km[1], c = Km[2];
    float d = Km[3], e = Km[4], f = Km[5];
    float g = Km[6], h = Km[7], i = Km[8];
    float A00 = e * i - f * h, A01 = c * h - b * i, A02 = b * f - c * e;
    float A10 = f * g - d * i, A11 = a * i - c * g, A12 = c * d - a * f;
    float A20 = d * h - e * g, A21 = b * g - a * h, A22 = a * e - b * d;
    float det = a * A00 + b * A10 + c * A20;
    float r = 1.0f / det;
    float Ki[9] = {A00 * r, A01 * r, A02 * r,
                   A10 * r, A11 * r, A12 * r,
                   A20 * r, A21 * r, A22 * r};
    float R[4][4];
    for (int rr = 0; rr < 4; ++rr) {
        for (int cc = 0; cc < 3; ++cc)
            R[rr][cc] = Tm[rr * 4 + 0] * Ki[0 * 3 + cc]
                      + Tm[rr * 4 + 1] * Ki[1 * 3 + cc]
                      + Tm[rr * 4 + 2] * Ki[2 * 3 + cc];
        R[rr][3] = Tm[rr * 4 + 3];
    }
    const float s[3] = {2.5f, 2.5f, 2.5f};
    const float t[3] = {100.0f, 100.0f, 2.5f};
    for (int rr = 0; rr < 3; ++rr)
        for (int cc = 0; cc < 4; ++cc)
            M[rr * 4 + cc] = s[rr] * R[rr][cc] + t[rr] * R[3][cc];
}

// ---------------------------------------------------------------------------
// Kernel 0: setup.  One wave computes M and the conservative crop AABB of the
// sampling frustum (per-depth-slab 4-corner AABB, clipped to the volume,
// unioned over the 56 slabs, widened by >=1 voxel for trilinear corners plus
// fp slack).  Header layout in d_ws (floats): [0..11] = M; ints at [12..17] =
// x0, y0, z0, CW, CH, CD.  Both downstream kernels read this header, so both
// sides use bit-identical crop values.
// ---------------------------------------------------------------------------
__global__ __launch_bounds__(64)
void vt_setup(const float* __restrict__ Km, const float* __restrict__ Tm,
              float* __restrict__ hdr) {
    __shared__ float sM[12];
    const int t = threadIdx.x;
    if (t == 0) compute_M(Km, Tm, sM);
    __syncthreads();
    float m[12];
#pragma unroll
    for (int i = 0; i < 12; ++i) m[i] = sM[i];

    int bx0 = 0x7fffffff, by0 = 0x7fffffff, bz0 = 0x7fffffff;
    int bx1 = -1, by1 = -1, bz1 = -1;
    if (t < FD) {
        const float gd = 2.0f + (float)t * (56.0f / 55.0f);
        const float HIq[3] = {(float)VW, (float)VH, (float)VD};
        float lo[3], hi[3];
        bool ok = true;
#pragma unroll
        for (int q = 0; q < 3; ++q) {
            // slab coords are affine in image (x,y): f = gd*(M0*x+M1*y+M2)+M3
            const float axx  = m[q * 4 + 0] * gd * 1599.0f;
            const float byy  = m[q * 4 + 1] * gd * 899.0f;
            const float base = m[q * 4 + 2] * gd + m[q * 4 + 3];
            lo[q] = base + fminf(axx, 0.0f) + fminf(byy, 0.0f);
            hi[q] = base + fmaxf(axx, 0.0f) + fmaxf(byy, 0.0f);
            if (!(lo[q] < HIq[q] && hi[q] > -1.0f)) ok = false;  // slab misses volume
        }
        if (ok) {
            const int dmax[3] = {VW - 1, VH - 1, VD - 1};
#pragma unroll
            for (int q = 0; q < 3; ++q) {
                int i0 = (int)floorf(fmaxf(lo[q], -2.0f)) - 1;
                int i1 = (int)floorf(fminf(hi[q], HIq[q] + 1.0f)) + 2;
                i0 = max(i0, 0);
                i1 = min(i1, dmax[q]);
                if (q == 0) { bx0 = i0; bx1 = i1; }
                else if (q == 1) { by0 = i0; by1 = i1; }
                else { bz0 = i0; bz1 = i1; }
            }
        }
    }
#pragma unroll
    for (int s = 1; s < 64; s <<= 1) {
        bx0 = min(bx0, __shfl_xor(bx0, s));
        bx1 = max(bx1, __shfl_xor(bx1, s));
        by0 = min(by0, __shfl_xor(by0, s));
        by1 = max(by1, __shfl_xor(by1, s));
        bz0 = min(bz0, __shfl_xor(bz0, s));
        bz1 = max(bz1, __shfl_xor(bz1, s));
    }
    if (t == 0) {
        if (bx1 < bx0 || by1 < by0 || bz1 < bz0) {
            // no slab intersects the volume: all weights are zero everywhere;
            // keep a 1-voxel crop so clamped (zero-weight) reads stay in-bounds
            bx0 = by0 = bz0 = 0; bx1 = by1 = bz1 = 0;
        }
#pragma unroll
        for (int i = 0; i < 12; ++i) hdr[i] = m[i];
        int* hi = (int*)hdr;
        hi[12] = bx0; hi[13] = by0; hi[14] = bz0;
        hi[15] = bx1 - bx0 + 1;   // CW
        hi[16] = by1 - by0 + 1;   // CH
        hi[17] = bz1 - bz0 + 1;   // CD
    }
}

// ---------------------------------------------------------------------------
// Kernel 1: frustum-sparse transpose+downconvert vol (C,S) fp32 -> cropped
// channel-last volT (CD*CH*CW, C) fp16.  Block skip = crop-AABB test (cheap)
// OR the proven wedge half-space test.  In-crop voxels of surviving blocks are
// written at compacted addresses; everything else stays harness poison (finite
// fp16), which the sampler only ever reads with exactly-zero weights.
// ---------------------------------------------------------------------------
__global__ __launch_bounds__(256)
void vt_transpose_h(const float* __restrict__ vol, const float* __restrict__ hdr,
                    _Float16* __restrict__ volT) {
    __shared__ float tile[256 * 33];
    __shared__ int sh[8];   // 0:skip 1:x0 2:y0 3:z0 4:CW 5:CH 6:CD 7:CH*CW
    const int t  = threadIdx.x;
    const int s0 = blockIdx.x * 256;

    if (t == 0) {
        const int* hint = (const int*)hdr;
        const int cx0 = hint[12], cy0 = hint[13], cz0 = hint[14];
        const int cw = hint[15], chh = hint[16], cd = hint[17];
        const int send = s0 + 255;
        const int z0 = s0 / (VH * VW), z1 = send / (VH * VW);
        int ry0 = 0, ry1 = VH - 1;
        if (z0 == z1) {
            const int r0 = s0 - z0 * (VH * VW);
            ry0 = r0 / VW;
            ry1 = (r0 + 255) / VW;
        }
        int skip = 0;
        // crop-AABB skip (a 256-voxel tile always spans all x, so x never culls)
        if (z1 < cz0 || z0 > cz0 + cd - 1) skip = 1;
        if (ry1 < cy0 || ry0 > cy0 + chh - 1) skip = 1;
        if (!skip) {
            // wedge half-space test (unchanged, M read from header)
            const float b00 = hdr[0], b01 = hdr[1], b02 = hdr[2],  tx3 = hdr[3];
            const float b10 = hdr[4], b11 = hdr[5], b12 = hdr[6],  ty3 = hdr[7];
            const float b20 = hdr[8], b21 = hdr[9], b22 = hdr[10], tz3 = hdr[11];
            const float C00 = b11 * b22 - b12 * b21;
            const float C01 = b02 * b21 - b01 * b22;
            const float C02 = b01 * b12 - b02 * b11;
            const float C10 = b12 * b20 - b10 * b22;
            const float C11 = b00 * b22 - b02 * b20;
            const float C12 = b02 * b10 - b00 * b12;
            const float C20 = b10 * b21 - b11 * b20;
            const float C21 = b01 * b20 - b00 * b21;
            const float C22 = b00 * b11 - b01 * b10;
            const float det = b00 * C00 + b01 * C10 + b02 * C20;
            if (fabsf(det) > 1e-12f) {
                const float r = 1.0f / det;
                const float ix0 = C00 * r, ix1 = C01 * r, ix2 = C02 * r;
                const float iy0 = C10 * r, iy1 = C11 * r, iy2 = C12 * r;
                const float iz0 = C20 * r, iz1 = C21 * r, iz2 = C22 * r;
                const float cx = -(ix0 * tx3 + ix1 * ty3 + ix2 * tz3);
                const float cy = -(iy0 * tx3 + iy1 * ty3 + iy2 * tz3);
                const float cz = -(iz0 * tx3 + iz1 * ty3 + iz2 * tz3);
                const float EXP = 1.25f;
                const float lo[3] = {0.0f - EXP, (float)ry0 - EXP, (float)z0 - EXP};
                const float hi[3] = {(float)(VW - 1) + EXP, (float)ry1 + EXP, (float)z1 + EXP};
                const float SLK = 10.0f;
                const float gc[6][3] = {
                    { iz0,  iz1,  iz2},
                    {-iz0, -iz1, -iz2},
                    { ix0,  ix1,  ix2},
                    {1599.f*iz0 - ix0, 1599.f*iz1 - ix1, 1599.f*iz2 - ix2},
                    { iy0,  iy1,  iy2},
                    { 899.f*iz0 - iy0,  899.f*iz1 - iy1,  899.f*iz2 - iy2},
                };
                const float gd0[6] = {cz - 2.0f + 0.1f, 58.0f + 0.1f - cz,
                                      cx + SLK, 1599.f * cz - cx + SLK,
                                      cy + SLK,  899.f * cz - cy + SLK};
                for (int q = 0; q < 6; ++q) {
                    float mx = gd0[q];
                    for (int j = 0; j < 3; ++j)
                        mx += (gc[q][j] > 0.0f) ? gc[q][j] * hi[j] : gc[q][j] * lo[j];
                    if (mx < 0.0f) { skip = 1; break; }
                }
            }
        }
        sh[0] = skip; sh[1] = cx0; sh[2] = cy0; sh[3] = cz0;
        sh[4] = cw; sh[5] = chh; sh[6] = cd; sh[7] = chh * cw;
    }
    __syncthreads();
    if (sh[0]) return;

#pragma unroll
    for (int c = 0; c < NC; ++c)
        tile[t * 33 + c] = __builtin_nontemporal_load(vol + (size_t)c * CSTRIDE + s0 + t);
    __syncthreads();
    const int rs  = t >> 2;         // row-in-tile 0..63
    const int ch8 = (t & 3) * 8;    // channel octet 0,8,16,24
    const int cx0 = sh[1], cy0 = sh[2], cz0 = sh[3];
    const int cw = sh[4], chh = sh[5], cd = sh[6], chw = sh[7];
#pragma unroll
    for (int j = 0; j < 4; ++j) {
        const int sl = j * 64 + rs;
        const int s  = s0 + sl;
        const int z   = s / (VH * VW);
        const int rem = s - z * (VH * VW);
        const int y   = rem / VW;
        const int x   = rem - y * VW;
        const int ex = x - cx0, ey = y - cy0, ez = z - cz0;
        if (ex < 0 || ex >= cw || ey < 0 || ey >= chh || ez < 0 || ez >= cd) continue;
        const float* r = &tile[sl * 33 + ch8];
        h8 pk = {(_Float16)r[0], (_Float16)r[1], (_Float16)r[2], (_Float16)r[3],
                 (_Float16)r[4], (_Float16)r[5], (_Float16)r[6], (_Float16)r[7]};
        *(h8*)(volT + ((size_t)(ez * chw + ey * cw + ex) << 5) + ch8) = pk;  // 16B store
    }
}

// ---------------------------------------------------------------------------
// Kernel 2: sampler on cropped channel-last fp16 volT.
// Wave = 8 pixels x 8 channel-quads; each lane loads h4 (8B) per corner.
// Corner indices are clamped INTO the crop box (identity for every
// nonzero-weight corner; zero-weight corners read finite in-crop data).
// Blocks are XCD-swizzled so each XCD L2 owns a contiguous pixel band.
// ---------------------------------------------------------------------------
__global__ __launch_bounds__(256)
void vt_sample_th(const _Float16* __restrict__ volT,
                  const float* __restrict__ hdr,
                  float* __restrict__ out) {
    __shared__ float sM[12];
    __shared__ int sc[8];   // X0,X1,Y0,Y1,Z0,Z1,CW,CHW
    if (threadIdx.x < 12) sM[threadIdx.x] = hdr[threadIdx.x];
    if (threadIdx.x == 0) {
        const int* hint = (const int*)hdr;
        const int x0 = hint[12], y0 = hint[13], z0 = hint[14];
        const int cw = hint[15], chh = hint[16], cd = hint[17];
        sc[0] = x0; sc[1] = x0 + cw - 1;
        sc[2] = y0; sc[3] = y0 + chh - 1;
        sc[4] = z0; sc[5] = z0 + cd - 1;
        sc[6] = cw; sc[7] = chh * cw;
    }
    __syncthreads();

    const int t    = threadIdx.x;
    const int wv   = t >> 6;        // 0..3
    const int lane = t & 63;
    const int chq  = lane & 7;      // channel-quad 0..7
    const int pixl = lane >> 3;     // 0..7
    const int c0   = chq * 4;

    // bijective XCD-aware block swizzle: 8 contiguous pixel-band chunks
    const int nwg = NPIX / 32;                  // 700
    const int qc  = nwg >> 3, rc = nwg & 7;     // 87, 4
    const int xcd = (int)blockIdx.x & 7;
    const int idx = (int)blockIdx.x >> 3;
    const int sb  = (xcd < rc ? xcd * (qc + 1) : rc * (qc + 1) + (xcd - rc) * qc) + idx;

    const int p    = sb * 32 + wv * 8 + pixl;   // 0..22399
    const int py   = p / FW;
    const int px   = p - py * FW;

    const float gx = (float)px * (1599.0f / 199.0f);
    const float gy = (float)py * (899.0f / 111.0f);

    const float m03 = sM[3], m13 = sM[7], m23 = sM[11];
    const float ax = sM[0] * gx + sM[1] * gy + sM[2];
    const float ay = sM[4] * gx + sM[5] * gy + sM[6];
    const float az = sM[8] * gx + sM[9] * gy + sM[10];

    const int X0 = sc[0], X1 = sc[1], Y0 = sc[2], Y1 = sc[3];
    const int Z0 = sc[4], Z1 = sc[5], CWr = sc[6], CHWr = sc[7];

    // closed-form hit interval (coords affine in gd), widened 1 step
    float dlo = 2.0f, dhi = 58.0f;
    {
        const float A[3]  = {ax, ay, az};
        const float Bv[3] = {m03, m13, m23};
        const float HI[3] = {(float)VW, (float)VH, (float)VD};
        for (int q = 0; q < 3; ++q) {
            float a = A[q], b = Bv[q], hi = HI[q];
            if (a > 0.0f)      { dlo = fmaxf(dlo, (-1.0f - b) / a); dhi = fminf(dhi, (hi - b) / a); }
            else if (a < 0.0f) { dlo = fmaxf(dlo, (hi - b) / a);    dhi = fminf(dhi, (-1.0f - b) / a); }
            else if (!(b > -1.0f && b < hi)) { dlo = 1e30f; dhi = -1e30f; }
        }
    }
    int klo = (int)ceilf((dlo - 2.0f) * (55.0f / 56.0f));
    int khi = (int)floorf((dhi - 2.0f) * (55.0f / 56.0f));
    klo = max(klo - 1, 0);
    khi = min(khi + 1, FD - 1);

    float acc0 = 0.0f, acc1 = 0.0f, acc2 = 0.0f, acc3 = 0.0f;

#pragma unroll 2
    for (int k = klo; k <= khi; ++k) {
        const float gd = 2.0f + (float)k * (56.0f / 55.0f);
        const float fx = fmaf(ax, gd, m03);
        const float fy = fmaf(ay, gd, m13);
        const float fz = fmaf(az, gd, m23);

        const bool valid = (fx > -1.0f) && (fx < (float)VW) &&
                           (fy > -1.0f) && (fy < (float)VH) &&
                           (fz > -1.0f) && (fz < (float)VD);
        const float vm = valid ? 1.0f : 0.0f;

        const float xf = floorf(fx), yf = floorf(fy), zf = floorf(fz);
        const float tx = fx - xf, ty = fy - yf, tz = fz - zf;
        const int ix = (int)xf, iy = (int)yf, iz = (int)zf;

        const float wx0 = (ix >= 0)     ? (1.0f - tx) : 0.0f;
        const float wx1 = (ix < VW - 1) ? tx          : 0.0f;
        const float wy0 = (iy >= 0)     ? (1.0f - ty) : 0.0f;
        const float wy1 = (iy < VH - 1) ? ty          : 0.0f;
        const float wz0 = ((iz >= 0)     ? (1.0f - tz) : 0.0f) * vm;
        const float wz1 = ((iz < VD - 1) ? tz          : 0.0f) * vm;

        // clamp into crop box: identity for nonzero-weight corners
        const int xi0 = min(max(ix,     X0), X1) - X0;
        const int xi1 = min(max(ix + 1, X0), X1) - X0;
        const int yo0 = (min(max(iy,     Y0), Y1) - Y0) * CWr;
        const int yo1 = (min(max(iy + 1, Y0), Y1) - Y0) * CWr;
        const int zo0 = (min(max(iz,     Z0), Z1) - Z0) * CHWr;
        const int zo1 = (min(max(iz + 1, Z0), Z1) - Z0) * CHWr;

        const int o000 = ((zo0 + yo0 + xi0) << 5) + c0;
        const int o001 = ((zo0 + yo0 + xi1) << 5) + c0;
        const int o010 = ((zo0 + yo1 + xi0) << 5) + c0;
        const int o011 = ((zo0 + yo1 + xi1) << 5) + c0;
        const int o100 = ((zo1 + yo0 + xi0) << 5) + c0;
        const int o101 = ((zo1 + yo0 + xi1) << 5) + c0;
        const int o110 = ((zo1 + yo1 + xi0) << 5) + c0;
        const int o111 = ((zo1 + yo1 + xi1) << 5) + c0;

        const h4 v000 = *(const uh4*)(volT + o000);
        const h4 v001 = *(const uh4*)(volT + o001);
        const h4 v010 = *(const uh4*)(volT + o010);
        const h4 v011 = *(const uh4*)(volT + o011);
        const h4 v100 = *(const uh4*)(volT + o100);
        const h4 v101 = *(const uh4*)(volT + o101);
        const h4 v110 = *(const uh4*)(volT + o110);
        const h4 v111 = *(const uh4*)(volT + o111);

        const float w000 = wz0 * wy0 * wx0, w001 = wz0 * wy0 * wx1;
        const float w010 = wz0 * wy1 * wx0, w011 = wz0 * wy1 * wx1;
        const float w100 = wz1 * wy0 * wx0, w101 = wz1 * wy0 * wx1;
        const float w110 = wz1 * wy1 * wx0, w111 = wz1 * wy1 * wx1;

        acc0 += w000 * (float)v000.x + w001 * (float)v001.x
              + w010 * (float)v010.x + w011 * (float)v011.x
              + w100 * (float)v100.x + w101 * (float)v101.x
              + w110 * (float)v110.x + w111 * (float)v111.x;
        acc1 += w000 * (float)v000.y + w001 * (float)v001.y
              + w010 * (float)v010.y + w011 * (float)v011.y
              + w100 * (float)v100.y + w101 * (float)v101.y
              + w110 * (float)v110.y + w111 * (float)v111.y;
        acc2 += w000 * (float)v000.z + w001 * (float)v001.z
              + w010 * (float)v010.z + w011 * (float)v011.z
              + w100 * (float)v100.z + w101 * (float)v101.z
              + w110 * (float)v110.z + w111 * (float)v111.z;
        acc3 += w000 * (float)v000.w + w001 * (float)v001.w
              + w010 * (float)v010.w + w011 * (float)v011.w
              + w110 * (float)v110.w + w111 * (float)v111.w
              + w100 * (float)v100.w + w101 * (float)v101.w;
    }

    out[(size_t)(c0 + 0) * NPIX + p] = acc0;
    out[(size_t)(c0 + 1) * NPIX + p] = acc1;
    out[(size_t)(c0 + 2) * NPIX + p] = acc2;
    out[(size_t)(c0 + 3) * NPIX + p] = acc3;
}

// ---------------------------------------------------------------------------
// Fallback (proven Round-6 kernel): channel-major direct sampling, used only
// if the workspace is too small for the transposed volume.
// ---------------------------------------------------------------------------
__global__ __launch_bounds__(256)
void vt_sample_direct(const float* __restrict__ vol,
                      const float* __restrict__ Km,
                      const float* __restrict__ Tm,
                      float* __restrict__ out) {
    __shared__ float sM[12];
    if (threadIdx.x == 0) compute_M(Km, Tm, sM);
    __syncthreads();

    const int cg   = blockIdx.x & 3;
    const int pg   = blockIdx.x >> 2;
    const int lane = threadIdx.x & 63;
    const int wv   = threadIdx.x >> 6;
    const int c0   = (cg * 4 + wv) * 2;
    const int p    = pg * 64 + lane;
    const int py   = p / FW;
    const int px   = p - py * FW;

    const float gx = (float)px * (1599.0f / 199.0f);
    const float gy = (float)py * (899.0f / 111.0f);

    const float m03 = sM[3], m13 = sM[7], m23 = sM[11];
    const float ax = sM[0] * gx + sM[1] * gy + sM[2];
    const float ay = sM[4] * gx + sM[5] * gy + sM[6];
    const float az = sM[8] * gx + sM[9] * gy + sM[10];

    float dlo = 2.0f, dhi = 58.0f;
    {
        const float A[3]  = {ax, ay, az};
        const float Bv[3] = {m03, m13, m23};
        const float HI[3] = {(float)VW, (float)VH, (float)VD};
        for (int q = 0; q < 3; ++q) {
            float a = A[q], b = Bv[q], hi = HI[q];
            if (a > 0.0f)      { dlo = fmaxf(dlo, (-1.0f - b) / a); dhi = fminf(dhi, (hi - b) / a); }
            else if (a < 0.0f) { dlo = fmaxf(dlo, (hi - b) / a);    dhi = fminf(dhi, (-1.0f - b) / a); }
            else if (!(b > -1.0f && b < hi)) { dlo = 1e30f; dhi = -1e30f; }
        }
    }
    int klo = (int)ceilf((dlo - 2.0f) * (55.0f / 56.0f));
    int khi = (int)floorf((dhi - 2.0f) * (55.0f / 56.0f));
    klo = max(klo - 1, 0);
    khi = min(khi + 1, FD - 1);

    const float* __restrict__ volc0 = vol + (size_t)c0 * CSTRIDE;
    const float* __restrict__ volc1 = volc0 + CSTRIDE;
    float acc0 = 0.0f, acc1 = 0.0f;

#pragma unroll 2
    for (int k = klo; k <= khi; ++k) {
        const float gd = 2.0f + (float)k * (56.0f / 55.0f);
        const float fx = fmaf(ax, gd, m03);
        const float fy = fmaf(ay, gd, m13);
        const float fz = fmaf(az, gd, m23);

        const bool valid = (fx > -1.0f) && (fx < (float)VW) &&
                           (fy > -1.0f) && (fy < (float)VH) &&
                           (fz > -1.0f) && (fz < (float)VD);
        const float vm = valid ? 1.0f : 0.0f;

        const float xf = floorf(fx), yf = floorf(fy), zf = floorf(fz);
        const float tx = fx - xf, ty = fy - yf, tz = fz - zf;
        const int ix = (int)xf, iy = (int)yf, iz = (int)zf;

        float wlo = (ix >= 0) ? (1.0f - tx) : tx;
        wlo = (ix >= VW - 1) ? 0.0f : wlo;
        float whi = (ix >= 0) ? tx : 0.0f;
        whi = (ix >= VW - 1) ? (1.0f - tx) : whi;

        const float wy0 = (iy >= 0)     ? (1.0f - ty) : 0.0f;
        const float wy1 = (iy < VH - 1) ? ty          : 0.0f;
        const float wz0 = ((iz >= 0)     ? (1.0f - tz) : 0.0f) * vm;
        const float wz1 = ((iz < VD - 1) ? tz          : 0.0f) * vm;
        const float w00 = wz0 * wy0, w01 = wz0 * wy1;
        const float w10 = wz1 * wy0, w11 = wz1 * wy1;

        const int xi0 = min(max(ix, 0), VW - 2);
        const int yo0 = min(max(iy,     0), VH - 1) * VW;
        const int yo1 = min(max(iy + 1, 0), VH - 1) * VW;
        const int zo0 = min(max(iz,     0), VD - 1) * (VH * VW);
        const int zo1 = min(max(iz + 1, 0), VD - 1) * (VH * VW);

        const int o00 = zo0 + yo0 + xi0, o01 = zo0 + yo1 + xi0;
        const int o10 = zo1 + yo0 + xi0, o11 = zo1 + yo1 + xi0;

        const f2v a00 = *(const uf2v4*)(volc0 + o00);
        const f2v a01 = *(const uf2v4*)(volc0 + o01);
        const f2v a10 = *(const uf2v4*)(volc0 + o10);
        const f2v a11 = *(const uf2v4*)(volc0 + o11);
        const f2v b00 = *(const uf2v4*)(volc1 + o00);
        const f2v b01 = *(const uf2v4*)(volc1 + o01);
        const f2v b10 = *(const uf2v4*)(volc1 + o10);
        const f2v b11 = *(const uf2v4*)(volc1 + o11);

        acc0 += w00 * (wlo * a00.x + whi * a00.y) + w01 * (wlo * a01.x + whi * a01.y)
              + w10 * (wlo * a10.x + whi * a10.y) + w11 * (wlo * a11.x + whi * a11.y);
        acc1 += w00 * (wlo * b00.x + whi * b00.y) + w01 * (wlo * b01.x + whi * b01.y)
              + w10 * (wlo * b10.x + whi * b10.y) + w11 * (wlo * b11.x + whi * b11.y);
    }

    out[c0 * NPIX + p]       = acc0;
    out[(c0 + 1) * NPIX + p] = acc1;
}

extern "C" void kernel_launch(void* const* d_in, const int* in_sizes, int n_in,
                              void* d_out, int out_size, void* d_ws, size_t ws_size,
                              hipStream_t stream) {
    (void)in_sizes; (void)n_in; (void)out_size;
    const float* vol = (const float*)d_in[0]; // (1,32,16,200,200) fp32
    const float* Km  = (const float*)d_in[1]; // (1,3,3) fp32
    const float* Tm  = (const float*)d_in[2]; // (1,4,4) fp32
    float* out = (float*)d_out;               // (1,32,112,200) fp32

    const size_t need = 256 + (size_t)NS * NC * sizeof(_Float16); // hdr + worst-case volT
    if (ws_size >= need) {
        float* hdr = (float*)d_ws;
        _Float16* volT = (_Float16*)((char*)d_ws + 256);
        vt_setup<<<dim3(1), dim3(64), 0, stream>>>(Km, Tm, hdr);
        vt_transpose_h<<<dim3(NS / 256), dim3(256), 0, stream>>>(vol, hdr, volT);
        vt_sample_th<<<dim3(NPIX / 32), dim3(256), 0, stream>>>(volT, hdr, out);
    } else {
        vt_sample_direct<<<dim3(1400), dim3(256), 0, stream>>>(vol, Km, Tm, out);
    }
}

// Round 2
// 143.998 us; speedup vs baseline: 1.1116x; 1.1116x over previous
//
#include <hip/hip_runtime.h>

// Problem constants (from reference config)
#define FD 56          // depth samples: linspace(2, 58, 56)
#define FH 112         // 900 / 8
#define FW 200         // 1600 / 8
#define VD 16          // volume D
#define VH 200         // volume H
#define VW 200         // volume W
#define NC 32          // channels
#define NPIX (FH * FW)         // 22400
#define NS   (VD * VH * VW)    // 640000 spatial voxels
#define CSTRIDE NS             // floats per channel (channel-major input)

typedef float f2v __attribute__((ext_vector_type(2)));
typedef f2v uf2v4 __attribute__((aligned(4)));   // fallback: 8B vec, 4B-align safe
typedef _Float16 h4 __attribute__((ext_vector_type(4)));
typedef h4 uh4 __attribute__((aligned(8)));
typedef _Float16 h8 __attribute__((ext_vector_type(8)));

// Compute fused projection matrix M = e2f @ T @ [[K^-1,0],[0,1]] (12 floats,
// rows = (W,H,D) feature coords). Cheap enough that EVERY thread runs it
// redundantly (~150 VALU) -- removes serial thread-0 + broadcast syncs and
// guarantees bit-identical M in both kernels.
__device__ inline void compute_M(const float* Km, const float* Tm, float* M) {
    float a = Km[0], b = Km[1], c = Km[2];
    float d = Km[3], e = Km[4], f = Km[5];
    float g = Km[6], h = Km[7], i = Km[8];
    float A00 = e * i - f * h, A01 = c * h - b * i, A02 = b * f - c * e;
    float A10 = f * g - d * i, A11 = a * i - c * g, A12 = c * d - a * f;
    float A20 = d * h - e * g, A21 = b * g - a * h, A22 = a * e - b * d;
    float det = a * A00 + b * A10 + c * A20;
    float r = 1.0f / det;
    float Ki[9] = {A00 * r, A01 * r, A02 * r,
                   A10 * r, A11 * r, A12 * r,
                   A20 * r, A21 * r, A22 * r};
    float R[4][4];
    for (int rr = 0; rr < 4; ++rr) {
        for (int cc = 0; cc < 3; ++cc)
            R[rr][cc] = Tm[rr * 4 + 0] * Ki[0 * 3 + cc]
                      + Tm[rr * 4 + 1] * Ki[1 * 3 + cc]
                      + Tm[rr * 4 + 2] * Ki[2 * 3 + cc];
        R[rr][3] = Tm[rr * 4 + 3];
    }
    const float s[3] = {2.5f, 2.5f, 2.5f};
    const float t[3] = {100.0f, 100.0f, 2.5f};
    for (int rr = 0; rr < 3; ++rr)
        for (int cc = 0; cc < 4; ++cc)
            M[rr * 4 + cc] = s[rr] * R[rr][cc] + t[rr] * R[3][cc];
}

// Conservative crop AABB of the sampling frustum: per-depth-slab 4-corner AABB
// (coords affine in image x,y), clipped to the volume, unioned over 56 slabs,
// widened >=1 voxel for trilinear corners + fp slack. HW-verified in round 1.
// Every wave computes it redundantly via shfl (all lanes end with the result,
// no LDS, no syncthreads); deterministic => identical in both kernels.
__device__ inline void compute_crop(const float* m, int& cx0, int& cy0, int& cz0,
                                    int& cw, int& ch, int& cd) {
    const int l = threadIdx.x & 63;
    int bx0 = 0x7fffffff, by0 = 0x7fffffff, bz0 = 0x7fffffff;
    int bx1 = -1, by1 = -1, bz1 = -1;
    if (l < FD) {
        const float gd = 2.0f + (float)l * (56.0f / 55.0f);
        const float HIq[3] = {(float)VW, (float)VH, (float)VD};
        float lo[3], hi[3];
        bool ok = true;
#pragma unroll
        for (int q = 0; q < 3; ++q) {
            const float axx  = m[q * 4 + 0] * gd * 1599.0f;
            const float byy  = m[q * 4 + 1] * gd * 899.0f;
            const float base = m[q * 4 + 2] * gd + m[q * 4 + 3];
            lo[q] = base + fminf(axx, 0.0f) + fminf(byy, 0.0f);
            hi[q] = base + fmaxf(axx, 0.0f) + fmaxf(byy, 0.0f);
            if (!(lo[q] < HIq[q] && hi[q] > -1.0f)) ok = false;  // slab misses volume
        }
        if (ok) {
            const int dmax[3] = {VW - 1, VH - 1, VD - 1};
#pragma unroll
            for (int q = 0; q < 3; ++q) {
                int i0 = (int)floorf(fmaxf(lo[q], -2.0f)) - 1;
                int i1 = (int)floorf(fminf(hi[q], HIq[q] + 1.0f)) + 2;
                i0 = max(i0, 0);
                i1 = min(i1, dmax[q]);
                if (q == 0) { bx0 = i0; bx1 = i1; }
                else if (q == 1) { by0 = i0; by1 = i1; }
                else { bz0 = i0; bz1 = i1; }
            }
        }
    }
#pragma unroll
    for (int s = 1; s < 64; s <<= 1) {
        bx0 = min(bx0, __shfl_xor(bx0, s));
        bx1 = max(bx1, __shfl_xor(bx1, s));
        by0 = min(by0, __shfl_xor(by0, s));
        by1 = max(by1, __shfl_xor(by1, s));
        bz0 = min(bz0, __shfl_xor(bz0, s));
        bz1 = max(bz1, __shfl_xor(bz1, s));
    }
    if (bx1 < bx0 || by1 < by0 || bz1 < bz0) {
        // no slab intersects: all weights zero everywhere; keep a 1-voxel crop
        // so clamped (zero-weight) reads stay in-bounds
        bx0 = by0 = bz0 = 0; bx1 = by1 = bz1 = 0;
    }
    cx0 = bx0; cy0 = by0; cz0 = bz0;
    cw = bx1 - bx0 + 1; ch = by1 - by0 + 1; cd = bz1 - bz0 + 1;
}

// Wedge (camera frustum) half-space block cull -- proven round-0 margins.
// lo/hi: block AABB in absolute volume coords, pre-expanded by caller.
__device__ inline int wedge_skip(const float* M, const float lo[3], const float hi[3]) {
    const float b00 = M[0], b01 = M[1], b02 = M[2],  tx3 = M[3];
    const float b10 = M[4], b11 = M[5], b12 = M[6],  ty3 = M[7];
    const float b20 = M[8], b21 = M[9], b22 = M[10], tz3 = M[11];
    const float C00 = b11 * b22 - b12 * b21;
    const float C01 = b02 * b21 - b01 * b22;
    const float C02 = b01 * b12 - b02 * b11;
    const float C10 = b12 * b20 - b10 * b22;
    const float C11 = b00 * b22 - b02 * b20;
    const float C12 = b02 * b10 - b00 * b12;
    const float C20 = b10 * b21 - b11 * b20;
    const float C21 = b01 * b20 - b00 * b21;
    const float C22 = b00 * b11 - b01 * b10;
    const float det = b00 * C00 + b01 * C10 + b02 * C20;
    if (!(fabsf(det) > 1e-12f)) return 0;
    const float r = 1.0f / det;
    const float ix0 = C00 * r, ix1 = C01 * r, ix2 = C02 * r;
    const float iy0 = C10 * r, iy1 = C11 * r, iy2 = C12 * r;
    const float iz0 = C20 * r, iz1 = C21 * r, iz2 = C22 * r;
    const float cx = -(ix0 * tx3 + ix1 * ty3 + ix2 * tz3);
    const float cy = -(iy0 * tx3 + iy1 * ty3 + iy2 * tz3);
    const float cz = -(iz0 * tx3 + iz1 * ty3 + iz2 * tz3);
    const float SLK = 10.0f;   // generous absolute slack (keep-direction)
    const float gc[6][3] = {
        { iz0,  iz1,  iz2},                                       // w_z - 2
        {-iz0, -iz1, -iz2},                                       // 58 - w_z
        { ix0,  ix1,  ix2},                                       // w_x
        {1599.f*iz0 - ix0, 1599.f*iz1 - ix1, 1599.f*iz2 - ix2},   // 1599 w_z - w_x
        { iy0,  iy1,  iy2},                                       // w_y
        { 899.f*iz0 - iy0,  899.f*iz1 - iy1,  899.f*iz2 - iy2},   // 899 w_z - w_y
    };
    const float gd0[6] = {cz - 2.0f + 0.1f, 58.0f + 0.1f - cz,
                          cx + SLK, 1599.f * cz - cx + SLK,
                          cy + SLK,  899.f * cz - cy + SLK};
    for (int q = 0; q < 6; ++q) {
        float mx = gd0[q];
        for (int j = 0; j < 3; ++j)
            mx += (gc[q][j] > 0.0f) ? gc[q][j] * hi[j] : gc[q][j] * lo[j];
        if (mx < 0.0f) return 1;
    }
    return 0;
}

// ---------------------------------------------------------------------------
// Kernel 1: crop-compacted transpose+downconvert vol (C,S) fp32 -> cropped
// channel-last fp16 volT (CD*CH*CW voxels, 64B per voxel).  Blocks iterate
// COMPACTED space directly: reads touch only crop columns (runs of cw floats),
// writes are perfectly contiguous.  Grid = worst case; tail blocks exit.
// Unwritten (wedge-skipped) voxels keep harness poison (finite fp16); the
// sampler reads those only with exactly-zero weights.
// ---------------------------------------------------------------------------
__global__ __launch_bounds__(256)
void vt_transpose_c(const float* __restrict__ vol, _Float16* __restrict__ volT,
                    const float* __restrict__ Km, const float* __restrict__ Tm) {
    __shared__ float tile[256 * 33];
    const int t = threadIdx.x;

    float M[12];
    compute_M(Km, Tm, M);
    int x0, y0, z0, cw, ch, cd;
    compute_crop(M, x0, y0, z0, cw, ch, cd);
    const int chw = ch * cw;
    const int tot = cd * chw;
    const int cb0 = blockIdx.x * 256;
    if (cb0 >= tot) return;                 // uniform: tail block

    // block AABB in absolute volume coords -> wedge cull (uniform decision)
    {
        const int clast = min(cb0 + 255, tot - 1);
        const int ez0 = cb0 / chw, ez1 = clast / chw;
        int ey0 = 0, ey1 = ch - 1;
        if (ez0 == ez1) {
            const int r0 = cb0 - ez0 * chw;
            ey0 = r0 / cw;
            ey1 = (clast - ez0 * chw) / cw;
        }
        const float EXP = 1.25f;
        const float lo[3] = {(float)x0 - EXP, (float)(y0 + ey0) - EXP, (float)(z0 + ez0) - EXP};
        const float hi[3] = {(float)(x0 + cw - 1) + EXP, (float)(y0 + ey1) + EXP, (float)(z0 + ez1) + EXP};
        if (wedge_skip(M, lo, hi)) return;  // uniform: every thread agrees
    }

    const int cidx = cb0 + t;
    const bool live = cidx < tot;
    int lin = 0;
    if (live) {
        const int ez = cidx / chw;
        const int r1 = cidx - ez * chw;
        const int ey = r1 / cw;
        const int ex = r1 - ey * cw;
        lin = (z0 + ez) * (VH * VW) + (y0 + ey) * VW + (x0 + ex);
    }
    if (live) {
#pragma unroll
        for (int c = 0; c < NC; ++c)
            tile[t * 33 + c] = __builtin_nontemporal_load(vol + (size_t)c * CSTRIDE + lin);
    }
    __syncthreads();
    const int rs  = t >> 2;         // row-in-tile 0..63
    const int ch8 = (t & 3) * 8;    // channel octet 0,8,16,24
#pragma unroll
    for (int j = 0; j < 4; ++j) {
        const int sl = j * 64 + rs;
        if (cb0 + sl >= tot) continue;
        const float* r = &tile[sl * 33 + ch8];
        h8 pk = {(_Float16)r[0], (_Float16)r[1], (_Float16)r[2], (_Float16)r[3],
                 (_Float16)r[4], (_Float16)r[5], (_Float16)r[6], (_Float16)r[7]};
        *(h8*)(volT + ((size_t)(cb0 + sl) << 5) + ch8) = pk;  // 16B store, 16B-aligned
    }
}

// ---------------------------------------------------------------------------
// Kernel 2: sampler on cropped channel-last fp16 volT.
// Wave = 8 pixels x 8 channel-quads; each lane loads h4 (8B) per corner.
// Corner indices clamped INTO the crop box (identity for every nonzero-weight
// corner; zero-weight corners read finite in-crop data).  Default round-robin
// block order (NO band swizzle -- round 1 showed banding causes cross-XCD
// load imbalance: ray length varies strongly with image row).
// ---------------------------------------------------------------------------
__global__ __launch_bounds__(256)
void vt_sample_c(const _Float16* __restrict__ volT,
                 const float* __restrict__ Km,
                 const float* __restrict__ Tm,
                 float* __restrict__ out) {
    float Mv[12];
    compute_M(Km, Tm, Mv);
    int x0, y0, z0, cw, chh, cd;
    compute_crop(Mv, x0, y0, z0, cw, chh, cd);
    const int X0 = x0, X1 = x0 + cw - 1;
    const int Y0 = y0, Y1 = y0 + chh - 1;
    const int Z0 = z0, Z1 = z0 + cd - 1;
    const int CWr = cw, CHWr = chh * cw;

    const int t    = threadIdx.x;
    const int wv   = t >> 6;        // 0..3
    const int lane = t & 63;
    const int chq  = lane & 7;      // channel-quad 0..7
    const int pixl = lane >> 3;     // 0..7
    const int c0   = chq * 4;
    const int p    = blockIdx.x * 32 + wv * 8 + pixl;  // 0..22399
    const int py   = p / FW;
    const int px   = p - py * FW;

    const float gx = (float)px * (1599.0f / 199.0f);
    const float gy = (float)py * (899.0f / 111.0f);

    const float m03 = Mv[3], m13 = Mv[7], m23 = Mv[11];
    const float ax = Mv[0] * gx + Mv[1] * gy + Mv[2];
    const float ay = Mv[4] * gx + Mv[5] * gy + Mv[6];
    const float az = Mv[8] * gx + Mv[9] * gy + Mv[10];

    // closed-form hit interval (coords affine in gd), widened 1 step
    float dlo = 2.0f, dhi = 58.0f;
    {
        const float A[3]  = {ax, ay, az};
        const float Bv[3] = {m03, m13, m23};
        const float HI[3] = {(float)VW, (float)VH, (float)VD};
        for (int q = 0; q < 3; ++q) {
            float a = A[q], b = Bv[q], hi = HI[q];
            if (a > 0.0f)      { dlo = fmaxf(dlo, (-1.0f - b) / a); dhi = fminf(dhi, (hi - b) / a); }
            else if (a < 0.0f) { dlo = fmaxf(dlo, (hi - b) / a);    dhi = fminf(dhi, (-1.0f - b) / a); }
            else if (!(b > -1.0f && b < hi)) { dlo = 1e30f; dhi = -1e30f; }
        }
    }
    int klo = (int)ceilf((dlo - 2.0f) * (55.0f / 56.0f));
    int khi = (int)floorf((dhi - 2.0f) * (55.0f / 56.0f));
    klo = max(klo - 1, 0);
    khi = min(khi + 1, FD - 1);

    float acc0 = 0.0f, acc1 = 0.0f, acc2 = 0.0f, acc3 = 0.0f;

#pragma unroll 2
    for (int k = klo; k <= khi; ++k) {
        const float gd = 2.0f + (float)k * (56.0f / 55.0f);
        const float fx = fmaf(ax, gd, m03);
        const float fy = fmaf(ay, gd, m13);
        const float fz = fmaf(az, gd, m23);

        const bool valid = (fx > -1.0f) && (fx < (float)VW) &&
                           (fy > -1.0f) && (fy < (float)VH) &&
                           (fz > -1.0f) && (fz < (float)VD);
        const float vm = valid ? 1.0f : 0.0f;

        const float xf = floorf(fx), yf = floorf(fy), zf = floorf(fz);
        const float tx = fx - xf, ty = fy - yf, tz = fz - zf;
        const int ix = (int)xf, iy = (int)yf, iz = (int)zf;

        const float wx0 = (ix >= 0)     ? (1.0f - tx) : 0.0f;
        const float wx1 = (ix < VW - 1) ? tx          : 0.0f;
        const float wy0 = (iy >= 0)     ? (1.0f - ty) : 0.0f;
        const float wy1 = (iy < VH - 1) ? ty          : 0.0f;
        const float wz0 = ((iz >= 0)     ? (1.0f - tz) : 0.0f) * vm;
        const float wz1 = ((iz < VD - 1) ? tz          : 0.0f) * vm;

        // clamp into crop box: identity for nonzero-weight corners
        const int xi0 = min(max(ix,     X0), X1) - X0;
        const int xi1 = min(max(ix + 1, X0), X1) - X0;
        const int yo0 = (min(max(iy,     Y0), Y1) - Y0) * CWr;
        const int yo1 = (min(max(iy + 1, Y0), Y1) - Y0) * CWr;
        const int zo0 = (min(max(iz,     Z0), Z1) - Z0) * CHWr;
        const int zo1 = (min(max(iz + 1, Z0), Z1) - Z0) * CHWr;

        const int o000 = ((zo0 + yo0 + xi0) << 5) + c0;
        const int o001 = ((zo0 + yo0 + xi1) << 5) + c0;
        const int o010 = ((zo0 + yo1 + xi0) << 5) + c0;
        const int o011 = ((zo0 + yo1 + xi1) << 5) + c0;
        const int o100 = ((zo1 + yo0 + xi0) << 5) + c0;
        const int o101 = ((zo1 + yo0 + xi1) << 5) + c0;
        const int o110 = ((zo1 + yo1 + xi0) << 5) + c0;
        const int o111 = ((zo1 + yo1 + xi1) << 5) + c0;

        const h4 v000 = *(const uh4*)(volT + o000);
        const h4 v001 = *(const uh4*)(volT + o001);
        const h4 v010 = *(const uh4*)(volT + o010);
        const h4 v011 = *(const uh4*)(volT + o011);
        const h4 v100 = *(const uh4*)(volT + o100);
        const h4 v101 = *(const uh4*)(volT + o101);
        const h4 v110 = *(const uh4*)(volT + o110);
        const h4 v111 = *(const uh4*)(volT + o111);

        const float w000 = wz0 * wy0 * wx0, w001 = wz0 * wy0 * wx1;
        const float w010 = wz0 * wy1 * wx0, w011 = wz0 * wy1 * wx1;
        const float w100 = wz1 * wy0 * wx0, w101 = wz1 * wy0 * wx1;
        const float w110 = wz1 * wy1 * wx0, w111 = wz1 * wy1 * wx1;

        acc0 += w000 * (float)v000.x + w001 * (float)v001.x
              + w010 * (float)v010.x + w011 * (float)v011.x
              + w100 * (float)v100.x + w101 * (float)v101.x
              + w110 * (float)v110.x + w111 * (float)v111.x;
        acc1 += w000 * (float)v000.y + w001 * (float)v001.y
              + w010 * (float)v010.y + w011 * (float)v011.y
              + w100 * (float)v100.y + w101 * (float)v101.y
              + w110 * (float)v110.y + w111 * (float)v111.y;
        acc2 += w000 * (float)v000.z + w001 * (float)v001.z
              + w010 * (float)v010.z + w011 * (float)v011.z
              + w100 * (float)v100.z + w101 * (float)v101.z
              + w110 * (float)v110.z + w111 * (float)v111.z;
        acc3 += w000 * (float)v000.w + w001 * (float)v001.w
              + w010 * (float)v010.w + w011 * (float)v011.w
              + w100 * (float)v100.w + w101 * (float)v101.w
              + w110 * (float)v110.w + w111 * (float)v111.w;
    }

    out[(size_t)(c0 + 0) * NPIX + p] = acc0;
    out[(size_t)(c0 + 1) * NPIX + p] = acc1;
    out[(size_t)(c0 + 2) * NPIX + p] = acc2;
    out[(size_t)(c0 + 3) * NPIX + p] = acc3;
}

// ---------------------------------------------------------------------------
// Fallback (proven Round-6 kernel): channel-major direct sampling, used only
// if the workspace is too small for the transposed volume.
// ---------------------------------------------------------------------------
__global__ __launch_bounds__(256)
void vt_sample_direct(const float* __restrict__ vol,
                      const float* __restrict__ Km,
                      const float* __restrict__ Tm,
                      float* __restrict__ out) {
    __shared__ float sM[12];
    if (threadIdx.x == 0) compute_M(Km, Tm, sM);
    __syncthreads();

    const int cg   = blockIdx.x & 3;
    const int pg   = blockIdx.x >> 2;
    const int lane = threadIdx.x & 63;
    const int wv   = threadIdx.x >> 6;
    const int c0   = (cg * 4 + wv) * 2;
    const int p    = pg * 64 + lane;
    const int py   = p / FW;
    const int px   = p - py * FW;

    const float gx = (float)px * (1599.0f / 199.0f);
    const float gy = (float)py * (899.0f / 111.0f);

    const float m03 = sM[3], m13 = sM[7], m23 = sM[11];
    const float ax = sM[0] * gx + sM[1] * gy + sM[2];
    const float ay = sM[4] * gx + sM[5] * gy + sM[6];
    const float az = sM[8] * gx + sM[9] * gy + sM[10];

    float dlo = 2.0f, dhi = 58.0f;
    {
        const float A[3]  = {ax, ay, az};
        const float Bv[3] = {m03, m13, m23};
        const float HI[3] = {(float)VW, (float)VH, (float)VD};
        for (int q = 0; q < 3; ++q) {
            float a = A[q], b = Bv[q], hi = HI[q];
            if (a > 0.0f)      { dlo = fmaxf(dlo, (-1.0f - b) / a); dhi = fminf(dhi, (hi - b) / a); }
            else if (a < 0.0f) { dlo = fmaxf(dlo, (hi - b) / a);    dhi = fminf(dhi, (-1.0f - b) / a); }
            else if (!(b > -1.0f && b < hi)) { dlo = 1e30f; dhi = -1e30f; }
        }
    }
    int klo = (int)ceilf((dlo - 2.0f) * (55.0f / 56.0f));
    int khi = (int)floorf((dhi - 2.0f) * (55.0f / 56.0f));
    klo = max(klo - 1, 0);
    khi = min(khi + 1, FD - 1);

    const float* __restrict__ volc0 = vol + (size_t)c0 * CSTRIDE;
    const float* __restrict__ volc1 = volc0 + CSTRIDE;
    float acc0 = 0.0f, acc1 = 0.0f;

#pragma unroll 2
    for (int k = klo; k <= khi; ++k) {
        const float gd = 2.0f + (float)k * (56.0f / 55.0f);
        const float fx = fmaf(ax, gd, m03);
        const float fy = fmaf(ay, gd, m13);
        const float fz = fmaf(az, gd, m23);

        const bool valid = (fx > -1.0f) && (fx < (float)VW) &&
                           (fy > -1.0f) && (fy < (float)VH) &&
                           (fz > -1.0f) && (fz < (float)VD);
        const float vm = valid ? 1.0f : 0.0f;

        const float xf = floorf(fx), yf = floorf(fy), zf = floorf(fz);
        const float tx = fx - xf, ty = fy - yf, tz = fz - zf;
        const int ix = (int)xf, iy = (int)yf, iz = (int)zf;

        float wlo = (ix >= 0) ? (1.0f - tx) : tx;
        wlo = (ix >= VW - 1) ? 0.0f : wlo;
        float whi = (ix >= 0) ? tx : 0.0f;
        whi = (ix >= VW - 1) ? (1.0f - tx) : whi;

        const float wy0 = (iy >= 0)     ? (1.0f - ty) : 0.0f;
        const float wy1 = (iy < VH - 1) ? ty          : 0.0f;
        const float wz0 = ((iz >= 0)     ? (1.0f - tz) : 0.0f) * vm;
        const float wz1 = ((iz < VD - 1) ? tz          : 0.0f) * vm;
        const float w00 = wz0 * wy0, w01 = wz0 * wy1;
        const float w10 = wz1 * wy0, w11 = wz1 * wy1;

        const int xi0 = min(max(ix, 0), VW - 2);
        const int yo0 = min(max(iy,     0), VH - 1) * VW;
        const int yo1 = min(max(iy + 1, 0), VH - 1) * VW;
        const int zo0 = min(max(iz,     0), VD - 1) * (VH * VW);
        const int zo1 = min(max(iz + 1, 0), VD - 1) * (VH * VW);

        const int o00 = zo0 + yo0 + xi0, o01 = zo0 + yo1 + xi0;
        const int o10 = zo1 + yo0 + xi0, o11 = zo1 + yo1 + xi0;

        const f2v a00 = *(const uf2v4*)(volc0 + o00);
        const f2v a01 = *(const uf2v4*)(volc0 + o01);
        const f2v a10 = *(const uf2v4*)(volc0 + o10);
        const f2v a11 = *(const uf2v4*)(volc0 + o11);
        const f2v b00 = *(const uf2v4*)(volc1 + o00);
        const f2v b01 = *(const uf2v4*)(volc1 + o01);
        const f2v b10 = *(const uf2v4*)(volc1 + o10);
        const f2v b11 = *(const uf2v4*)(volc1 + o11);

        acc0 += w00 * (wlo * a00.x + whi * a00.y) + w01 * (wlo * a01.x + whi * a01.y)
              + w10 * (wlo * a10.x + whi * a10.y) + w11 * (wlo * a11.x + whi * a11.y);
        acc1 += w00 * (wlo * b00.x + whi * b00.y) + w01 * (wlo * b01.x + whi * b01.y)
              + w10 * (wlo * b10.x + whi * b10.y) + w11 * (wlo * b11.x + whi * b11.y);
    }

    out[c0 * NPIX + p]       = acc0;
    out[(c0 + 1) * NPIX + p] = acc1;
}

extern "C" void kernel_launch(void* const* d_in, const int* in_sizes, int n_in,
                              void* d_out, int out_size, void* d_ws, size_t ws_size,
                              hipStream_t stream) {
    (void)in_sizes; (void)n_in; (void)out_size;
    const float* vol = (const float*)d_in[0]; // (1,32,16,200,200) fp32
    const float* Km  = (const float*)d_in[1]; // (1,3,3) fp32
    const float* Tm  = (const float*)d_in[2]; // (1,4,4) fp32
    float* out = (float*)d_out;               // (1,32,112,200) fp32

    const size_t need = (size_t)NS * NC * sizeof(_Float16); // worst-case volT
    if (ws_size >= need) {
        _Float16* volT = (_Float16*)d_ws;
        vt_transpose_c<<<dim3(NS / 256), dim3(256), 0, stream>>>(vol, volT, Km, Tm);
        vt_sample_c<<<dim3(NPIX / 32), dim3(256), 0, stream>>>(volT, Km, Tm, out);
    } else {
        vt_sample_direct<<<dim3(1400), dim3(256), 0, stream>>>(vol, Km, Tm, out);
    }
}

// Round 3
// 137.971 us; speedup vs baseline: 1.1602x; 1.0437x over previous
//
#include <hip/hip_runtime.h>

// Problem constants (from reference config)
#define FD 56          // depth samples: linspace(2, 58, 56)
#define FH 112         // 900 / 8
#define FW 200         // 1600 / 8
#define VD 16          // volume D
#define VH 200         // volume H
#define VW 200         // volume W
#define NC 32          // channels
#define NPIX (FH * FW)         // 22400
#define NS   (VD * VH * VW)    // 640000 spatial voxels
#define CSTRIDE NS             // floats per channel (channel-major input)

typedef float f2v __attribute__((ext_vector_type(2)));
typedef f2v uf2v4 __attribute__((aligned(4)));   // fallback: 8B vec, 4B-align safe
typedef float f4v __attribute__((ext_vector_type(4)));
typedef _Float16 h4 __attribute__((ext_vector_type(4)));
typedef h4 uh4 __attribute__((aligned(8)));
typedef _Float16 h8 __attribute__((ext_vector_type(8)));

// Compute fused projection matrix M = e2f @ T @ [[K^-1,0],[0,1]] (12 floats,
// rows = (W,H,D) feature coords). Cheap enough that EVERY thread runs it
// redundantly (~150 VALU) -- removes serial thread-0 + broadcast syncs and
// guarantees bit-identical M in both kernels.
__device__ inline void compute_M(const float* Km, const float* Tm, float* M) {
    float a = Km[0], b = Km[1], c = Km[2];
    float d = Km[3], e = Km[4], f = Km[5];
    float g = Km[6], h = Km[7], i = Km[8];
    float A00 = e * i - f * h, A01 = c * h - b * i, A02 = b * f - c * e;
    float A10 = f * g - d * i, A11 = a * i - c * g, A12 = c * d - a * f;
    float A20 = d * h - e * g, A21 = b * g - a * h, A22 = a * e - b * d;
    float det = a * A00 + b * A10 + c * A20;
    float r = 1.0f / det;
    float Ki[9] = {A00 * r, A01 * r, A02 * r,
                   A10 * r, A11 * r, A12 * r,
                   A20 * r, A21 * r, A22 * r};
    float R[4][4];
    for (int rr = 0; rr < 4; ++rr) {
        for (int cc = 0; cc < 3; ++cc)
            R[rr][cc] = Tm[rr * 4 + 0] * Ki[0 * 3 + cc]
                      + Tm[rr * 4 + 1] * Ki[1 * 3 + cc]
                      + Tm[rr * 4 + 2] * Ki[2 * 3 + cc];
        R[rr][3] = Tm[rr * 4 + 3];
    }
    const float s[3] = {2.5f, 2.5f, 2.5f};
    const float t[3] = {100.0f, 100.0f, 2.5f};
    for (int rr = 0; rr < 3; ++rr)
        for (int cc = 0; cc < 4; ++cc)
            M[rr * 4 + cc] = s[rr] * R[rr][cc] + t[rr] * R[3][cc];
}

// Conservative crop AABB of the sampling frustum: per-depth-slab 4-corner AABB
// (coords affine in image x,y), clipped to the volume, unioned over 56 slabs,
// widened >=1 voxel for trilinear corners + fp slack. HW-verified in rounds 1-2.
// Every wave computes it redundantly via shfl (all lanes end with the result,
// no LDS, no syncthreads); deterministic => identical in both kernels.
__device__ inline void compute_crop(const float* m, int& cx0, int& cy0, int& cz0,
                                    int& cw, int& ch, int& cd) {
    const int l = threadIdx.x & 63;
    int bx0 = 0x7fffffff, by0 = 0x7fffffff, bz0 = 0x7fffffff;
    int bx1 = -1, by1 = -1, bz1 = -1;
    if (l < FD) {
        const float gd = 2.0f + (float)l * (56.0f / 55.0f);
        const float HIq[3] = {(float)VW, (float)VH, (float)VD};
        float lo[3], hi[3];
        bool ok = true;
#pragma unroll
        for (int q = 0; q < 3; ++q) {
            const float axx  = m[q * 4 + 0] * gd * 1599.0f;
            const float byy  = m[q * 4 + 1] * gd * 899.0f;
            const float base = m[q * 4 + 2] * gd + m[q * 4 + 3];
            lo[q] = base + fminf(axx, 0.0f) + fminf(byy, 0.0f);
            hi[q] = base + fmaxf(axx, 0.0f) + fmaxf(byy, 0.0f);
            if (!(lo[q] < HIq[q] && hi[q] > -1.0f)) ok = false;  // slab misses volume
        }
        if (ok) {
            const int dmax[3] = {VW - 1, VH - 1, VD - 1};
#pragma unroll
            for (int q = 0; q < 3; ++q) {
                int i0 = (int)floorf(fmaxf(lo[q], -2.0f)) - 1;
                int i1 = (int)floorf(fminf(hi[q], HIq[q] + 1.0f)) + 2;
                i0 = max(i0, 0);
                i1 = min(i1, dmax[q]);
                if (q == 0) { bx0 = i0; bx1 = i1; }
                else if (q == 1) { by0 = i0; by1 = i1; }
                else { bz0 = i0; bz1 = i1; }
            }
        }
    }
#pragma unroll
    for (int s = 1; s < 64; s <<= 1) {
        bx0 = min(bx0, __shfl_xor(bx0, s));
        bx1 = max(bx1, __shfl_xor(bx1, s));
        by0 = min(by0, __shfl_xor(by0, s));
        by1 = max(by1, __shfl_xor(by1, s));
        bz0 = min(bz0, __shfl_xor(bz0, s));
        bz1 = max(bz1, __shfl_xor(bz1, s));
    }
    if (bx1 < bx0 || by1 < by0 || bz1 < bz0) {
        // no slab intersects: all weights zero everywhere; keep a 1-voxel crop
        // so clamped (zero-weight) reads stay in-bounds
        bx0 = by0 = bz0 = 0; bx1 = by1 = bz1 = 0;
    }
    cx0 = bx0; cy0 = by0; cz0 = bz0;
    cw = bx1 - bx0 + 1; ch = by1 - by0 + 1; cd = bz1 - bz0 + 1;
}

// Wedge (camera frustum) half-space block cull -- proven round-0 margins.
// lo/hi: block AABB in absolute volume coords, pre-expanded by caller.
__device__ inline int wedge_skip(const float* M, const float lo[3], const float hi[3]) {
    const float b00 = M[0], b01 = M[1], b02 = M[2],  tx3 = M[3];
    const float b10 = M[4], b11 = M[5], b12 = M[6],  ty3 = M[7];
    const float b20 = M[8], b21 = M[9], b22 = M[10], tz3 = M[11];
    const float C00 = b11 * b22 - b12 * b21;
    const float C01 = b02 * b21 - b01 * b22;
    const float C02 = b01 * b12 - b02 * b11;
    const float C10 = b12 * b20 - b10 * b22;
    const float C11 = b00 * b22 - b02 * b20;
    const float C12 = b02 * b10 - b00 * b12;
    const float C20 = b10 * b21 - b11 * b20;
    const float C21 = b01 * b20 - b00 * b21;
    const float C22 = b00 * b11 - b01 * b10;
    const float det = b00 * C00 + b01 * C10 + b02 * C20;
    if (!(fabsf(det) > 1e-12f)) return 0;
    const float r = 1.0f / det;
    const float ix0 = C00 * r, ix1 = C01 * r, ix2 = C02 * r;
    const float iy0 = C10 * r, iy1 = C11 * r, iy2 = C12 * r;
    const float iz0 = C20 * r, iz1 = C21 * r, iz2 = C22 * r;
    const float cx = -(ix0 * tx3 + ix1 * ty3 + ix2 * tz3);
    const float cy = -(iy0 * tx3 + iy1 * ty3 + iy2 * tz3);
    const float cz = -(iz0 * tx3 + iz1 * ty3 + iz2 * tz3);
    const float SLK = 10.0f;   // generous absolute slack (keep-direction)
    const float gc[6][3] = {
        { iz0,  iz1,  iz2},                                       // w_z - 2
        {-iz0, -iz1, -iz2},                                       // 58 - w_z
        { ix0,  ix1,  ix2},                                       // w_x
        {1599.f*iz0 - ix0, 1599.f*iz1 - ix1, 1599.f*iz2 - ix2},   // 1599 w_z - w_x
        { iy0,  iy1,  iy2},                                       // w_y
        { 899.f*iz0 - iy0,  899.f*iz1 - iy1,  899.f*iz2 - iy2},   // 899 w_z - w_y
    };
    const float gd0[6] = {cz - 2.0f + 0.1f, 58.0f + 0.1f - cz,
                          cx + SLK, 1599.f * cz - cx + SLK,
                          cy + SLK,  899.f * cz - cy + SLK};
    for (int q = 0; q < 6; ++q) {
        float mx = gd0[q];
        for (int j = 0; j < 3; ++j)
            mx += (gc[q][j] > 0.0f) ? gc[q][j] * hi[j] : gc[q][j] * lo[j];
        if (mx < 0.0f) return 1;
    }
    return 0;
}

// ---------------------------------------------------------------------------
// Kernel 1: crop-compacted transpose+downconvert vol (C,S) fp32 -> cropped
// channel-last fp16 volT (CD*CH*CW voxels, 64B per voxel).  Unchanged from the
// verified round-2 kernel.
// ---------------------------------------------------------------------------
__global__ __launch_bounds__(256)
void vt_transpose_c(const float* __restrict__ vol, _Float16* __restrict__ volT,
                    const float* __restrict__ Km, const float* __restrict__ Tm) {
    __shared__ float tile[256 * 33];
    const int t = threadIdx.x;

    float M[12];
    compute_M(Km, Tm, M);
    int x0, y0, z0, cw, ch, cd;
    compute_crop(M, x0, y0, z0, cw, ch, cd);
    const int chw = ch * cw;
    const int tot = cd * chw;
    const int cb0 = blockIdx.x * 256;
    if (cb0 >= tot) return;                 // uniform: tail block

    // block AABB in absolute volume coords -> wedge cull (uniform decision)
    {
        const int clast = min(cb0 + 255, tot - 1);
        const int ez0 = cb0 / chw, ez1 = clast / chw;
        int ey0 = 0, ey1 = ch - 1;
        if (ez0 == ez1) {
            const int r0 = cb0 - ez0 * chw;
            ey0 = r0 / cw;
            ey1 = (clast - ez0 * chw) / cw;
        }
        const float EXP = 1.25f;
        const float lo[3] = {(float)x0 - EXP, (float)(y0 + ey0) - EXP, (float)(z0 + ez0) - EXP};
        const float hi[3] = {(float)(x0 + cw - 1) + EXP, (float)(y0 + ey1) + EXP, (float)(z0 + ez1) + EXP};
        if (wedge_skip(M, lo, hi)) return;  // uniform: every thread agrees
    }

    const int cidx = cb0 + t;
    const bool live = cidx < tot;
    int lin = 0;
    if (live) {
        const int ez = cidx / chw;
        const int r1 = cidx - ez * chw;
        const int ey = r1 / cw;
        const int ex = r1 - ey * cw;
        lin = (z0 + ez) * (VH * VW) + (y0 + ey) * VW + (x0 + ex);
    }
    if (live) {
#pragma unroll
        for (int c = 0; c < NC; ++c)
            tile[t * 33 + c] = __builtin_nontemporal_load(vol + (size_t)c * CSTRIDE + lin);
    }
    __syncthreads();
    const int rs  = t >> 2;         // row-in-tile 0..63
    const int ch8 = (t & 3) * 8;    // channel octet 0,8,16,24
#pragma unroll
    for (int j = 0; j < 4; ++j) {
        const int sl = j * 64 + rs;
        if (cb0 + sl >= tot) continue;
        const float* r = &tile[sl * 33 + ch8];
        h8 pk = {(_Float16)r[0], (_Float16)r[1], (_Float16)r[2], (_Float16)r[3],
                 (_Float16)r[4], (_Float16)r[5], (_Float16)r[6], (_Float16)r[7]};
        *(h8*)(volT + ((size_t)(cb0 + sl) << 5) + ch8) = pk;  // 16B store, 16B-aligned
    }
}

// ---------------------------------------------------------------------------
// Kernel 2: 2-way depth-split sampler on cropped channel-last fp16 volT.
// The sampler is gather-LATENCY-bound at 2.73 waves/SIMD (22400 px x 8 chq =
// 2800 waves on 1024 SIMDs).  Split each pixel's depth loop across TWO waves
// (kh=0: even k, kh=1: odd k) and reduce via 2KB LDS at block end:
// 1400 blocks x 4 waves = 5600 waves = 5.5/SIMD (~VGPR cap), doubling the
// latency-hiding pool.  Corner clamping into the crop box is the round-1/2
// verified logic.  Default round-robin block order (banding proved harmful).
// ---------------------------------------------------------------------------
__global__ __launch_bounds__(256)
void vt_sample_c(const _Float16* __restrict__ volT,
                 const float* __restrict__ Km,
                 const float* __restrict__ Tm,
                 float* __restrict__ out) {
    __shared__ f4v red[2][64];      // [pixgroup][lane] partial acc from kh=1
    float Mv[12];
    compute_M(Km, Tm, Mv);
    int x0, y0, z0, cw, chh, cd;
    compute_crop(Mv, x0, y0, z0, cw, chh, cd);
    const int X0 = x0, X1 = x0 + cw - 1;
    const int Y0 = y0, Y1 = y0 + chh - 1;
    const int Z0 = z0, Z1 = z0 + cd - 1;
    const int CWr = cw, CHWr = chh * cw;

    const int t    = threadIdx.x;
    const int wv   = t >> 6;        // 0..3
    const int kh   = wv & 1;        // depth-half: 0=even k, 1=odd k
    const int pg   = wv >> 1;       // pixel-group 0..1
    const int lane = t & 63;
    const int chq  = lane & 7;      // channel-quad 0..7
    const int pixl = lane >> 3;     // 0..7
    const int c0   = chq * 4;
    const int p    = blockIdx.x * 16 + pg * 8 + pixl;  // 0..22399
    const int py   = p / FW;
    const int px   = p - py * FW;

    const float gx = (float)px * (1599.0f / 199.0f);
    const float gy = (float)py * (899.0f / 111.0f);

    const float m03 = Mv[3], m13 = Mv[7], m23 = Mv[11];
    const float ax = Mv[0] * gx + Mv[1] * gy + Mv[2];
    const float ay = Mv[4] * gx + Mv[5] * gy + Mv[6];
    const float az = Mv[8] * gx + Mv[9] * gy + Mv[10];

    // closed-form hit interval (coords affine in gd), widened 1 step
    float dlo = 2.0f, dhi = 58.0f;
    {
        const float A[3]  = {ax, ay, az};
        const float Bv[3] = {m03, m13, m23};
        const float HI[3] = {(float)VW, (float)VH, (float)VD};
        for (int q = 0; q < 3; ++q) {
            float a = A[q], b = Bv[q], hi = HI[q];
            if (a > 0.0f)      { dlo = fmaxf(dlo, (-1.0f - b) / a); dhi = fminf(dhi, (hi - b) / a); }
            else if (a < 0.0f) { dlo = fmaxf(dlo, (hi - b) / a);    dhi = fminf(dhi, (-1.0f - b) / a); }
            else if (!(b > -1.0f && b < hi)) { dlo = 1e30f; dhi = -1e30f; }
        }
    }
    int klo = (int)ceilf((dlo - 2.0f) * (55.0f / 56.0f));
    int khi = (int)floorf((dhi - 2.0f) * (55.0f / 56.0f));
    klo = max(klo - 1, 0);
    khi = min(khi + 1, FD - 1);

    float acc0 = 0.0f, acc1 = 0.0f, acc2 = 0.0f, acc3 = 0.0f;

#pragma unroll 2
    for (int k = klo + kh; k <= khi; k += 2) {
        const float gd = 2.0f + (float)k * (56.0f / 55.0f);
        const float fx = fmaf(ax, gd, m03);
        const float fy = fmaf(ay, gd, m13);
        const float fz = fmaf(az, gd, m23);

        const bool valid = (fx > -1.0f) && (fx < (float)VW) &&
                           (fy > -1.0f) && (fy < (float)VH) &&
                           (fz > -1.0f) && (fz < (float)VD);
        const float vm = valid ? 1.0f : 0.0f;

        const float xf = floorf(fx), yf = floorf(fy), zf = floorf(fz);
        const float tx = fx - xf, ty = fy - yf, tz = fz - zf;
        const int ix = (int)xf, iy = (int)yf, iz = (int)zf;

        const float wx0 = (ix >= 0)     ? (1.0f - tx) : 0.0f;
        const float wx1 = (ix < VW - 1) ? tx          : 0.0f;
        const float wy0 = (iy >= 0)     ? (1.0f - ty) : 0.0f;
        const float wy1 = (iy < VH - 1) ? ty          : 0.0f;
        const float wz0 = ((iz >= 0)     ? (1.0f - tz) : 0.0f) * vm;
        const float wz1 = ((iz < VD - 1) ? tz          : 0.0f) * vm;

        // clamp into crop box: identity for nonzero-weight corners
        const int xi0 = min(max(ix,     X0), X1) - X0;
        const int xi1 = min(max(ix + 1, X0), X1) - X0;
        const int yo0 = (min(max(iy,     Y0), Y1) - Y0) * CWr;
        const int yo1 = (min(max(iy + 1, Y0), Y1) - Y0) * CWr;
        const int zo0 = (min(max(iz,     Z0), Z1) - Z0) * CHWr;
        const int zo1 = (min(max(iz + 1, Z0), Z1) - Z0) * CHWr;

        const int o000 = ((zo0 + yo0 + xi0) << 5) + c0;
        const int o001 = ((zo0 + yo0 + xi1) << 5) + c0;
        const int o010 = ((zo0 + yo1 + xi0) << 5) + c0;
        const int o011 = ((zo0 + yo1 + xi1) << 5) + c0;
        const int o100 = ((zo1 + yo0 + xi0) << 5) + c0;
        const int o101 = ((zo1 + yo0 + xi1) << 5) + c0;
        const int o110 = ((zo1 + yo1 + xi0) << 5) + c0;
        const int o111 = ((zo1 + yo1 + xi1) << 5) + c0;

        const h4 v000 = *(const uh4*)(volT + o000);
        const h4 v001 = *(const uh4*)(volT + o001);
        const h4 v010 = *(const uh4*)(volT + o010);
        const h4 v011 = *(const uh4*)(volT + o011);
        const h4 v100 = *(const uh4*)(volT + o100);
        const h4 v101 = *(const uh4*)(volT + o101);
        const h4 v110 = *(const uh4*)(volT + o110);
        const h4 v111 = *(const uh4*)(volT + o111);

        const float w000 = wz0 * wy0 * wx0, w001 = wz0 * wy0 * wx1;
        const float w010 = wz0 * wy1 * wx0, w011 = wz0 * wy1 * wx1;
        const float w100 = wz1 * wy0 * wx0, w101 = wz1 * wy0 * wx1;
        const float w110 = wz1 * wy1 * wx0, w111 = wz1 * wy1 * wx1;

        acc0 += w000 * (float)v000.x + w001 * (float)v001.x
              + w010 * (float)v010.x + w011 * (float)v011.x
              + w100 * (float)v100.x + w101 * (float)v101.x
              + w110 * (float)v110.x + w111 * (float)v111.x;
        acc1 += w000 * (float)v000.y + w001 * (float)v001.y
              + w010 * (float)v010.y + w011 * (float)v011.y
              + w100 * (float)v100.y + w101 * (float)v101.y
              + w110 * (float)v110.y + w111 * (float)v111.y;
        acc2 += w000 * (float)v000.z + w001 * (float)v001.z
              + w010 * (float)v010.z + w011 * (float)v011.z
              + w100 * (float)v100.z + w101 * (float)v101.z
              + w110 * (float)v110.z + w111 * (float)v111.z;
        acc3 += w000 * (float)v000.w + w001 * (float)v001.w
              + w010 * (float)v010.w + w011 * (float)v011.w
              + w100 * (float)v100.w + w101 * (float)v101.w
              + w110 * (float)v110.w + w111 * (float)v111.w;
    }

    // cross-wave depth-half reduction (kh=1 -> LDS, kh=0 adds and stores)
    if (kh) {
        f4v a = {acc0, acc1, acc2, acc3};
        red[pg][lane] = a;
    }
    __syncthreads();
    if (!kh) {
        const f4v o = red[pg][lane];
        out[(size_t)(c0 + 0) * NPIX + p] = acc0 + o.x;
        out[(size_t)(c0 + 1) * NPIX + p] = acc1 + o.y;
        out[(size_t)(c0 + 2) * NPIX + p] = acc2 + o.z;
        out[(size_t)(c0 + 3) * NPIX + p] = acc3 + o.w;
    }
}

// ---------------------------------------------------------------------------
// Fallback (proven Round-6 kernel): channel-major direct sampling, used only
// if the workspace is too small for the transposed volume.
// ---------------------------------------------------------------------------
__global__ __launch_bounds__(256)
void vt_sample_direct(const float* __restrict__ vol,
                      const float* __restrict__ Km,
                      const float* __restrict__ Tm,
                      float* __restrict__ out) {
    __shared__ float sM[12];
    if (threadIdx.x == 0) compute_M(Km, Tm, sM);
    __syncthreads();

    const int cg   = blockIdx.x & 3;
    const int pg   = blockIdx.x >> 2;
    const int lane = threadIdx.x & 63;
    const int wv   = threadIdx.x >> 6;
    const int c0   = (cg * 4 + wv) * 2;
    const int p    = pg * 64 + lane;
    const int py   = p / FW;
    const int px   = p - py * FW;

    const float gx = (float)px * (1599.0f / 199.0f);
    const float gy = (float)py * (899.0f / 111.0f);

    const float m03 = sM[3], m13 = sM[7], m23 = sM[11];
    const float ax = sM[0] * gx + sM[1] * gy + sM[2];
    const float ay = sM[4] * gx + sM[5] * gy + sM[6];
    const float az = sM[8] * gx + sM[9] * gy + sM[10];

    float dlo = 2.0f, dhi = 58.0f;
    {
        const float A[3]  = {ax, ay, az};
        const float Bv[3] = {m03, m13, m23};
        const float HI[3] = {(float)VW, (float)VH, (float)VD};
        for (int q = 0; q < 3; ++q) {
            float a = A[q], b = Bv[q], hi = HI[q];
            if (a > 0.0f)      { dlo = fmaxf(dlo, (-1.0f - b) / a); dhi = fminf(dhi, (hi - b) / a); }
            else if (a < 0.0f) { dlo = fmaxf(dlo, (hi - b) / a);    dhi = fminf(dhi, (-1.0f - b) / a); }
            else if (!(b > -1.0f && b < hi)) { dlo = 1e30f; dhi = -1e30f; }
        }
    }
    int klo = (int)ceilf((dlo - 2.0f) * (55.0f / 56.0f));
    int khi = (int)floorf((dhi - 2.0f) * (55.0f / 56.0f));
    klo = max(klo - 1, 0);
    khi = min(khi + 1, FD - 1);

    const float* __restrict__ volc0 = vol + (size_t)c0 * CSTRIDE;
    const float* __restrict__ volc1 = volc0 + CSTRIDE;
    float acc0 = 0.0f, acc1 = 0.0f;

#pragma unroll 2
    for (int k = klo; k <= khi; ++k) {
        const float gd = 2.0f + (float)k * (56.0f / 55.0f);
        const float fx = fmaf(ax, gd, m03);
        const float fy = fmaf(ay, gd, m13);
        const float fz = fmaf(az, gd, m23);

        const bool valid = (fx > -1.0f) && (fx < (float)VW) &&
                           (fy > -1.0f) && (fy < (float)VH) &&
                           (fz > -1.0f) && (fz < (float)VD);
        const float vm = valid ? 1.0f : 0.0f;

        const float xf = floorf(fx), yf = floorf(fy), zf = floorf(fz);
        const float tx = fx - xf, ty = fy - yf, tz = fz - zf;
        const int ix = (int)xf, iy = (int)yf, iz = (int)zf;

        float wlo = (ix >= 0) ? (1.0f - tx) : tx;
        wlo = (ix >= VW - 1) ? 0.0f : wlo;
        float whi = (ix >= 0) ? tx : 0.0f;
        whi = (ix >= VW - 1) ? (1.0f - tx) : whi;

        const float wy0 = (iy >= 0)     ? (1.0f - ty) : 0.0f;
        const float wy1 = (iy < VH - 1) ? ty          : 0.0f;
        const float wz0 = ((iz >= 0)     ? (1.0f - tz) : 0.0f) * vm;
        const float wz1 = ((iz < VD - 1) ? tz          : 0.0f) * vm;
        const float w00 = wz0 * wy0, w01 = wz0 * wy1;
        const float w10 = wz1 * wy0, w11 = wz1 * wy1;

        const int xi0 = min(max(ix, 0), VW - 2);
        const int yo0 = min(max(iy,     0), VH - 1) * VW;
        const int yo1 = min(max(iy + 1, 0), VH - 1) * VW;
        const int zo0 = min(max(iz,     0), VD - 1) * (VH * VW);
        const int zo1 = min(max(iz + 1, 0), VD - 1) * (VH * VW);

        const int o00 = zo0 + yo0 + xi0, o01 = zo0 + yo1 + xi0;
        const int o10 = zo1 + yo0 + xi0, o11 = zo1 + yo1 + xi0;

        const f2v a00 = *(const uf2v4*)(volc0 + o00);
        const f2v a01 = *(const uf2v4*)(volc0 + o01);
        const f2v a10 = *(const uf2v4*)(volc0 + o10);
        const f2v a11 = *(const uf2v4*)(volc0 + o11);
        const f2v b00 = *(const uf2v4*)(volc1 + o00);
        const f2v b01 = *(const uf2v4*)(volc1 + o01);
        const f2v b10 = *(const uf2v4*)(volc1 + o10);
        const f2v b11 = *(const uf2v4*)(volc1 + o11);

        acc0 += w00 * (wlo * a00.x + whi * a00.y) + w01 * (wlo * a01.x + whi * a01.y)
              + w10 * (wlo * a10.x + whi * a10.y) + w11 * (wlo * a11.x + whi * a11.y);
        acc1 += w00 * (wlo * b00.x + whi * b00.y) + w01 * (wlo * b01.x + whi * b01.y)
              + w10 * (wlo * b10.x + whi * b10.y) + w11 * (wlo * b11.x + whi * b11.y);
    }

    out[c0 * NPIX + p]       = acc0;
    out[(c0 + 1) * NPIX + p] = acc1;
}

extern "C" void kernel_launch(void* const* d_in, const int* in_sizes, int n_in,
                              void* d_out, int out_size, void* d_ws, size_t ws_size,
                              hipStream_t stream) {
    (void)in_sizes; (void)n_in; (void)out_size;
    const float* vol = (const float*)d_in[0]; // (1,32,16,200,200) fp32
    const float* Km  = (const float*)d_in[1]; // (1,3,3) fp32
    const float* Tm  = (const float*)d_in[2]; // (1,4,4) fp32
    float* out = (float*)d_out;               // (1,32,112,200) fp32

    const size_t need = (size_t)NS * NC * sizeof(_Float16); // worst-case volT
    if (ws_size >= need) {
        _Float16* volT = (_Float16*)d_ws;
        vt_transpose_c<<<dim3(NS / 256), dim3(256), 0, stream>>>(vol, volT, Km, Tm);
        vt_sample_c<<<dim3(NPIX / 16), dim3(256), 0, stream>>>(volT, Km, Tm, out);
    } else {
        vt_sample_direct<<<dim3(1400), dim3(256), 0, stream>>>(vol, Km, Tm, out);
    }
}

// Round 4
// 134.138 us; speedup vs baseline: 1.1933x; 1.0286x over previous
//
#include <hip/hip_runtime.h>

// Problem constants (from reference config)
#define FD 56          // depth samples: linspace(2, 58, 56)
#define FH 112         // 900 / 8
#define FW 200         // 1600 / 8
#define VD 16          // volume D
#define VH 200         // volume H
#define VW 200         // volume W
#define NC 32          // channels
#define NPIX (FH * FW)         // 22400
#define NS   (VD * VH * VW)    // 640000 spatial voxels
#define CSTRIDE NS             // floats per channel (channel-major input)

typedef float f2v __attribute__((ext_vector_type(2)));
typedef f2v uf2v4 __attribute__((aligned(4)));   // fallback: 8B vec, 4B-align safe
typedef float f8v __attribute__((ext_vector_type(8)));
typedef _Float16 h8 __attribute__((ext_vector_type(8)));
typedef h8 uh8 __attribute__((aligned(16)));

// Compute fused projection matrix M = e2f @ T @ [[K^-1,0],[0,1]] (12 floats,
// rows = (W,H,D) feature coords). Cheap enough that EVERY thread runs it
// redundantly (~150 VALU) -- removes serial thread-0 + broadcast syncs and
// guarantees bit-identical M in both kernels.
__device__ inline void compute_M(const float* Km, const float* Tm, float* M) {
    float a = Km[0], b = Km[1], c = Km[2];
    float d = Km[3], e = Km[4], f = Km[5];
    float g = Km[6], h = Km[7], i = Km[8];
    float A00 = e * i - f * h, A01 = c * h - b * i, A02 = b * f - c * e;
    float A10 = f * g - d * i, A11 = a * i - c * g, A12 = c * d - a * f;
    float A20 = d * h - e * g, A21 = b * g - a * h, A22 = a * e - b * d;
    float det = a * A00 + b * A10 + c * A20;
    float r = 1.0f / det;
    float Ki[9] = {A00 * r, A01 * r, A02 * r,
                   A10 * r, A11 * r, A12 * r,
                   A20 * r, A21 * r, A22 * r};
    float R[4][4];
    for (int rr = 0; rr < 4; ++rr) {
        for (int cc = 0; cc < 3; ++cc)
            R[rr][cc] = Tm[rr * 4 + 0] * Ki[0 * 3 + cc]
                      + Tm[rr * 4 + 1] * Ki[1 * 3 + cc]
                      + Tm[rr * 4 + 2] * Ki[2 * 3 + cc];
        R[rr][3] = Tm[rr * 4 + 3];
    }
    const float s[3] = {2.5f, 2.5f, 2.5f};
    const float t[3] = {100.0f, 100.0f, 2.5f};
    for (int rr = 0; rr < 3; ++rr)
        for (int cc = 0; cc < 4; ++cc)
            M[rr * 4 + cc] = s[rr] * R[rr][cc] + t[rr] * R[3][cc];
}

// Conservative crop AABB of the sampling frustum: per-depth-slab 4-corner AABB
// (coords affine in image x,y), clipped to the volume, unioned over 56 slabs,
// widened >=1 voxel for trilinear corners + fp slack. HW-verified rounds 1-3.
// Every wave computes it redundantly via shfl (all lanes end with the result,
// no LDS, no syncthreads); deterministic => identical in both kernels.
__device__ inline void compute_crop(const float* m, int& cx0, int& cy0, int& cz0,
                                    int& cw, int& ch, int& cd) {
    const int l = threadIdx.x & 63;
    int bx0 = 0x7fffffff, by0 = 0x7fffffff, bz0 = 0x7fffffff;
    int bx1 = -1, by1 = -1, bz1 = -1;
    if (l < FD) {
        const float gd = 2.0f + (float)l * (56.0f / 55.0f);
        const float HIq[3] = {(float)VW, (float)VH, (float)VD};
        float lo[3], hi[3];
        bool ok = true;
#pragma unroll
        for (int q = 0; q < 3; ++q) {
            const float axx  = m[q * 4 + 0] * gd * 1599.0f;
            const float byy  = m[q * 4 + 1] * gd * 899.0f;
            const float base = m[q * 4 + 2] * gd + m[q * 4 + 3];
            lo[q] = base + fminf(axx, 0.0f) + fminf(byy, 0.0f);
            hi[q] = base + fmaxf(axx, 0.0f) + fmaxf(byy, 0.0f);
            if (!(lo[q] < HIq[q] && hi[q] > -1.0f)) ok = false;  // slab misses volume
        }
        if (ok) {
            const int dmax[3] = {VW - 1, VH - 1, VD - 1};
#pragma unroll
            for (int q = 0; q < 3; ++q) {
                int i0 = (int)floorf(fmaxf(lo[q], -2.0f)) - 1;
                int i1 = (int)floorf(fminf(hi[q], HIq[q] + 1.0f)) + 2;
                i0 = max(i0, 0);
                i1 = min(i1, dmax[q]);
                if (q == 0) { bx0 = i0; bx1 = i1; }
                else if (q == 1) { by0 = i0; by1 = i1; }
                else { bz0 = i0; bz1 = i1; }
            }
        }
    }
#pragma unroll
    for (int s = 1; s < 64; s <<= 1) {
        bx0 = min(bx0, __shfl_xor(bx0, s));
        bx1 = max(bx1, __shfl_xor(bx1, s));
        by0 = min(by0, __shfl_xor(by0, s));
        by1 = max(by1, __shfl_xor(by1, s));
        bz0 = min(bz0, __shfl_xor(bz0, s));
        bz1 = max(bz1, __shfl_xor(bz1, s));
    }
    if (bx1 < bx0 || by1 < by0 || bz1 < bz0) {
        // no slab intersects: all weights zero everywhere; keep a 1-voxel crop
        // so clamped (zero-weight) reads stay in-bounds
        bx0 = by0 = bz0 = 0; bx1 = by1 = bz1 = 0;
    }
    cx0 = bx0; cy0 = by0; cz0 = bz0;
    cw = bx1 - bx0 + 1; ch = by1 - by0 + 1; cd = bz1 - bz0 + 1;
}

// Wedge (camera frustum) half-space block cull -- proven round-0 margins.
// lo/hi: block AABB in absolute volume coords, pre-expanded by caller.
__device__ inline int wedge_skip(const float* M, const float lo[3], const float hi[3]) {
    const float b00 = M[0], b01 = M[1], b02 = M[2],  tx3 = M[3];
    const float b10 = M[4], b11 = M[5], b12 = M[6],  ty3 = M[7];
    const float b20 = M[8], b21 = M[9], b22 = M[10], tz3 = M[11];
    const float C00 = b11 * b22 - b12 * b21;
    const float C01 = b02 * b21 - b01 * b22;
    const float C02 = b01 * b12 - b02 * b11;
    const float C10 = b12 * b20 - b10 * b22;
    const float C11 = b00 * b22 - b02 * b20;
    const float C12 = b02 * b10 - b00 * b12;
    const float C20 = b10 * b21 - b11 * b20;
    const float C21 = b01 * b20 - b00 * b21;
    const float C22 = b00 * b11 - b01 * b10;
    const float det = b00 * C00 + b01 * C10 + b02 * C20;
    if (!(fabsf(det) > 1e-12f)) return 0;
    const float r = 1.0f / det;
    const float ix0 = C00 * r, ix1 = C01 * r, ix2 = C02 * r;
    const float iy0 = C10 * r, iy1 = C11 * r, iy2 = C12 * r;
    const float iz0 = C20 * r, iz1 = C21 * r, iz2 = C22 * r;
    const float cx = -(ix0 * tx3 + ix1 * ty3 + ix2 * tz3);
    const float cy = -(iy0 * tx3 + iy1 * ty3 + iy2 * tz3);
    const float cz = -(iz0 * tx3 + iz1 * ty3 + iz2 * tz3);
    const float SLK = 10.0f;   // generous absolute slack (keep-direction)
    const float gc[6][3] = {
        { iz0,  iz1,  iz2},                                       // w_z - 2
        {-iz0, -iz1, -iz2},                                       // 58 - w_z
        { ix0,  ix1,  ix2},                                       // w_x
        {1599.f*iz0 - ix0, 1599.f*iz1 - ix1, 1599.f*iz2 - ix2},   // 1599 w_z - w_x
        { iy0,  iy1,  iy2},                                       // w_y
        { 899.f*iz0 - iy0,  899.f*iz1 - iy1,  899.f*iz2 - iy2},   // 899 w_z - w_y
    };
    const float gd0[6] = {cz - 2.0f + 0.1f, 58.0f + 0.1f - cz,
                          cx + SLK, 1599.f * cz - cx + SLK,
                          cy + SLK,  899.f * cz - cy + SLK};
    for (int q = 0; q < 6; ++q) {
        float mx = gd0[q];
        for (int j = 0; j < 3; ++j)
            mx += (gc[q][j] > 0.0f) ? gc[q][j] * hi[j] : gc[q][j] * lo[j];
        if (mx < 0.0f) return 1;
    }
    return 0;
}

// ---------------------------------------------------------------------------
// Kernel 1: crop-compacted transpose+downconvert vol (C,S) fp32 -> cropped
// channel-last fp16 volT (CD*CH*CW voxels, 64B per voxel).  Unchanged from the
// verified round-2/3 kernel.
// ---------------------------------------------------------------------------
__global__ __launch_bounds__(256)
void vt_transpose_c(const float* __restrict__ vol, _Float16* __restrict__ volT,
                    const float* __restrict__ Km, const float* __restrict__ Tm) {
    __shared__ float tile[256 * 33];
    const int t = threadIdx.x;

    float M[12];
    compute_M(Km, Tm, M);
    int x0, y0, z0, cw, ch, cd;
    compute_crop(M, x0, y0, z0, cw, ch, cd);
    const int chw = ch * cw;
    const int tot = cd * chw;
    const int cb0 = blockIdx.x * 256;
    if (cb0 >= tot) return;                 // uniform: tail block

    // block AABB in absolute volume coords -> wedge cull (uniform decision)
    {
        const int clast = min(cb0 + 255, tot - 1);
        const int ez0 = cb0 / chw, ez1 = clast / chw;
        int ey0 = 0, ey1 = ch - 1;
        if (ez0 == ez1) {
            const int r0 = cb0 - ez0 * chw;
            ey0 = r0 / cw;
            ey1 = (clast - ez0 * chw) / cw;
        }
        const float EXP = 1.25f;
        const float lo[3] = {(float)x0 - EXP, (float)(y0 + ey0) - EXP, (float)(z0 + ez0) - EXP};
        const float hi[3] = {(float)(x0 + cw - 1) + EXP, (float)(y0 + ey1) + EXP, (float)(z0 + ez1) + EXP};
        if (wedge_skip(M, lo, hi)) return;  // uniform: every thread agrees
    }

    const int cidx = cb0 + t;
    const bool live = cidx < tot;
    int lin = 0;
    if (live) {
        const int ez = cidx / chw;
        const int r1 = cidx - ez * chw;
        const int ey = r1 / cw;
        const int ex = r1 - ey * cw;
        lin = (z0 + ez) * (VH * VW) + (y0 + ey) * VW + (x0 + ex);
    }
    if (live) {
#pragma unroll
        for (int c = 0; c < NC; ++c)
            tile[t * 33 + c] = __builtin_nontemporal_load(vol + (size_t)c * CSTRIDE + lin);
    }
    __syncthreads();
    const int rs  = t >> 2;         // row-in-tile 0..63
    const int ch8 = (t & 3) * 8;    // channel octet 0,8,16,24
#pragma unroll
    for (int j = 0; j < 4; ++j) {
        const int sl = j * 64 + rs;
        if (cb0 + sl >= tot) continue;
        const float* r = &tile[sl * 33 + ch8];
        h8 pk = {(_Float16)r[0], (_Float16)r[1], (_Float16)r[2], (_Float16)r[3],
                 (_Float16)r[4], (_Float16)r[5], (_Float16)r[6], (_Float16)r[7]};
        *(h8*)(volT + ((size_t)(cb0 + sl) << 5) + ch8) = pk;  // 16B store, 16B-aligned
    }
}

// ---------------------------------------------------------------------------
// Kernel 2: sampler, wave = 16 pixels x 4 channel-octets (h8 = 16B loads),
// 4-way depth split across the block's 4 waves.  vs round-3 (8px x 8chq x
// 2-way): same 5600-wave occupancy, but vmem load instructions per pixel
// halve and weight/address redundancy drops 8x -> 4x.  6KB LDS reduction.
// Corner clamping into the crop box is the rounds-1..3 verified logic.
// Default round-robin block order (banding proved harmful in round 1).
// ---------------------------------------------------------------------------
__global__ __launch_bounds__(256)
void vt_sample_c(const _Float16* __restrict__ volT,
                 const float* __restrict__ Km,
                 const float* __restrict__ Tm,
                 float* __restrict__ out) {
    __shared__ f8v red[3][64];      // partials from kh=1..3
    float Mv[12];
    compute_M(Km, Tm, Mv);
    int x0, y0, z0, cw, chh, cd;
    compute_crop(Mv, x0, y0, z0, cw, chh, cd);
    const int X0 = x0, X1 = x0 + cw - 1;
    const int Y0 = y0, Y1 = y0 + chh - 1;
    const int Z0 = z0, Z1 = z0 + cd - 1;
    const int CWr = cw, CHWr = chh * cw;

    const int t    = threadIdx.x;
    const int kh   = t >> 6;        // depth-phase 0..3 (wave index)
    const int lane = t & 63;
    const int chq  = lane & 3;      // channel-octet 0..3
    const int pixl = lane >> 2;     // 0..15
    const int c0   = chq * 8;
    const int p    = blockIdx.x * 16 + pixl;  // 0..22399
    const int py   = p / FW;
    const int px   = p - py * FW;

    const float gx = (float)px * (1599.0f / 199.0f);
    const float gy = (float)py * (899.0f / 111.0f);

    const float m03 = Mv[3], m13 = Mv[7], m23 = Mv[11];
    const float ax = Mv[0] * gx + Mv[1] * gy + Mv[2];
    const float ay = Mv[4] * gx + Mv[5] * gy + Mv[6];
    const float az = Mv[8] * gx + Mv[9] * gy + Mv[10];

    // closed-form hit interval (coords affine in gd), widened 1 step
    float dlo = 2.0f, dhi = 58.0f;
    {
        const float A[3]  = {ax, ay, az};
        const float Bv[3] = {m03, m13, m23};
        const float HI[3] = {(float)VW, (float)VH, (float)VD};
        for (int q = 0; q < 3; ++q) {
            float a = A[q], b = Bv[q], hi = HI[q];
            if (a > 0.0f)      { dlo = fmaxf(dlo, (-1.0f - b) / a); dhi = fminf(dhi, (hi - b) / a); }
            else if (a < 0.0f) { dlo = fmaxf(dlo, (hi - b) / a);    dhi = fminf(dhi, (-1.0f - b) / a); }
            else if (!(b > -1.0f && b < hi)) { dlo = 1e30f; dhi = -1e30f; }
        }
    }
    int klo = (int)ceilf((dlo - 2.0f) * (55.0f / 56.0f));
    int khi = (int)floorf((dhi - 2.0f) * (55.0f / 56.0f));
    klo = max(klo - 1, 0);
    khi = min(khi + 1, FD - 1);

    f8v acc = {0.0f, 0.0f, 0.0f, 0.0f, 0.0f, 0.0f, 0.0f, 0.0f};

#pragma unroll 2
    for (int k = klo + kh; k <= khi; k += 4) {
        const float gd = 2.0f + (float)k * (56.0f / 55.0f);
        const float fx = fmaf(ax, gd, m03);
        const float fy = fmaf(ay, gd, m13);
        const float fz = fmaf(az, gd, m23);

        const bool valid = (fx > -1.0f) && (fx < (float)VW) &&
                           (fy > -1.0f) && (fy < (float)VH) &&
                           (fz > -1.0f) && (fz < (float)VD);
        const float vm = valid ? 1.0f : 0.0f;

        const float xf = floorf(fx), yf = floorf(fy), zf = floorf(fz);
        const float tx = fx - xf, ty = fy - yf, tz = fz - zf;
        const int ix = (int)xf, iy = (int)yf, iz = (int)zf;

        const float wx0 = (ix >= 0)     ? (1.0f - tx) : 0.0f;
        const float wx1 = (ix < VW - 1) ? tx          : 0.0f;
        const float wy0 = (iy >= 0)     ? (1.0f - ty) : 0.0f;
        const float wy1 = (iy < VH - 1) ? ty          : 0.0f;
        const float wz0 = ((iz >= 0)     ? (1.0f - tz) : 0.0f) * vm;
        const float wz1 = ((iz < VD - 1) ? tz          : 0.0f) * vm;

        // clamp into crop box: identity for nonzero-weight corners
        const int xi0 = min(max(ix,     X0), X1) - X0;
        const int xi1 = min(max(ix + 1, X0), X1) - X0;
        const int yo0 = (min(max(iy,     Y0), Y1) - Y0) * CWr;
        const int yo1 = (min(max(iy + 1, Y0), Y1) - Y0) * CWr;
        const int zo0 = (min(max(iz,     Z0), Z1) - Z0) * CHWr;
        const int zo1 = (min(max(iz + 1, Z0), Z1) - Z0) * CHWr;

        const int o000 = ((zo0 + yo0 + xi0) << 5) + c0;
        const int o001 = ((zo0 + yo0 + xi1) << 5) + c0;
        const int o010 = ((zo0 + yo1 + xi0) << 5) + c0;
        const int o011 = ((zo0 + yo1 + xi1) << 5) + c0;
        const int o100 = ((zo1 + yo0 + xi0) << 5) + c0;
        const int o101 = ((zo1 + yo0 + xi1) << 5) + c0;
        const int o110 = ((zo1 + yo1 + xi0) << 5) + c0;
        const int o111 = ((zo1 + yo1 + xi1) << 5) + c0;

        const h8 v000 = *(const uh8*)(volT + o000);
        const h8 v001 = *(const uh8*)(volT + o001);
        const h8 v010 = *(const uh8*)(volT + o010);
        const h8 v011 = *(const uh8*)(volT + o011);
        const h8 v100 = *(const uh8*)(volT + o100);
        const h8 v101 = *(const uh8*)(volT + o101);
        const h8 v110 = *(const uh8*)(volT + o110);
        const h8 v111 = *(const uh8*)(volT + o111);

        const float w000 = wz0 * wy0 * wx0, w001 = wz0 * wy0 * wx1;
        const float w010 = wz0 * wy1 * wx0, w011 = wz0 * wy1 * wx1;
        const float w100 = wz1 * wy0 * wx0, w101 = wz1 * wy0 * wx1;
        const float w110 = wz1 * wy1 * wx0, w111 = wz1 * wy1 * wx1;

#pragma unroll
        for (int j = 0; j < 8; ++j) {
            acc[j] += w000 * (float)v000[j] + w001 * (float)v001[j]
                    + w010 * (float)v010[j] + w011 * (float)v011[j]
                    + w100 * (float)v100[j] + w101 * (float)v101[j]
                    + w110 * (float)v110[j] + w111 * (float)v111[j];
        }
    }

    // cross-wave depth-phase reduction (kh=1..3 -> LDS, kh=0 adds and stores)
    if (kh) red[kh - 1][lane] = acc;
    __syncthreads();
    if (kh == 0) {
        const f8v r0 = red[0][lane];
        const f8v r1 = red[1][lane];
        const f8v r2 = red[2][lane];
#pragma unroll
        for (int j = 0; j < 8; ++j) {
            out[(size_t)(c0 + j) * NPIX + p] = acc[j] + r0[j] + r1[j] + r2[j];
        }
    }
}

// ---------------------------------------------------------------------------
// Fallback (proven Round-6 kernel): channel-major direct sampling, used only
// if the workspace is too small for the transposed volume.
// ---------------------------------------------------------------------------
__global__ __launch_bounds__(256)
void vt_sample_direct(const float* __restrict__ vol,
                      const float* __restrict__ Km,
                      const float* __restrict__ Tm,
                      float* __restrict__ out) {
    __shared__ float sM[12];
    if (threadIdx.x == 0) compute_M(Km, Tm, sM);
    __syncthreads();

    const int cg   = blockIdx.x & 3;
    const int pg   = blockIdx.x >> 2;
    const int lane = threadIdx.x & 63;
    const int wv   = threadIdx.x >> 6;
    const int c0   = (cg * 4 + wv) * 2;
    const int p    = pg * 64 + lane;
    const int py   = p / FW;
    const int px   = p - py * FW;

    const float gx = (float)px * (1599.0f / 199.0f);
    const float gy = (float)py * (899.0f / 111.0f);

    const float m03 = sM[3], m13 = sM[7], m23 = sM[11];
    const float ax = sM[0] * gx + sM[1] * gy + sM[2];
    const float ay = sM[4] * gx + sM[5] * gy + sM[6];
    const float az = sM[8] * gx + sM[9] * gy + sM[10];

    float dlo = 2.0f, dhi = 58.0f;
    {
        const float A[3]  = {ax, ay, az};
        const float Bv[3] = {m03, m13, m23};
        const float HI[3] = {(float)VW, (float)VH, (float)VD};
        for (int q = 0; q < 3; ++q) {
            float a = A[q], b = Bv[q], hi = HI[q];
            if (a > 0.0f)      { dlo = fmaxf(dlo, (-1.0f - b) / a); dhi = fminf(dhi, (hi - b) / a); }
            else if (a < 0.0f) { dlo = fmaxf(dlo, (hi - b) / a);    dhi = fminf(dhi, (-1.0f - b) / a); }
            else if (!(b > -1.0f && b < hi)) { dlo = 1e30f; dhi = -1e30f; }
        }
    }
    int klo = (int)ceilf((dlo - 2.0f) * (55.0f / 56.0f));
    int khi = (int)floorf((dhi - 2.0f) * (55.0f / 56.0f));
    klo = max(klo - 1, 0);
    khi = min(khi + 1, FD - 1);

    const float* __restrict__ volc0 = vol + (size_t)c0 * CSTRIDE;
    const float* __restrict__ volc1 = volc0 + CSTRIDE;
    float acc0 = 0.0f, acc1 = 0.0f;

#pragma unroll 2
    for (int k = klo; k <= khi; ++k) {
        const float gd = 2.0f + (float)k * (56.0f / 55.0f);
        const float fx = fmaf(ax, gd, m03);
        const float fy = fmaf(ay, gd, m13);
        const float fz = fmaf(az, gd, m23);

        const bool valid = (fx > -1.0f) && (fx < (float)VW) &&
                           (fy > -1.0f) && (fy < (float)VH) &&
                           (fz > -1.0f) && (fz < (float)VD);
        const float vm = valid ? 1.0f : 0.0f;

        const float xf = floorf(fx), yf = floorf(fy), zf = floorf(fz);
        const float tx = fx - xf, ty = fy - yf, tz = fz - zf;
        const int ix = (int)xf, iy = (int)yf, iz = (int)zf;

        float wlo = (ix >= 0) ? (1.0f - tx) : tx;
        wlo = (ix >= VW - 1) ? 0.0f : wlo;
        float whi = (ix >= 0) ? tx : 0.0f;
        whi = (ix >= VW - 1) ? (1.0f - tx) : whi;

        const float wy0 = (iy >= 0)     ? (1.0f - ty) : 0.0f;
        const float wy1 = (iy < VH - 1) ? ty          : 0.0f;
        const float wz0 = ((iz >= 0)     ? (1.0f - tz) : 0.0f) * vm;
        const float wz1 = ((iz < VD - 1) ? tz          : 0.0f) * vm;
        const float w00 = wz0 * wy0, w01 = wz0 * wy1;
        const float w10 = wz1 * wy0, w11 = wz1 * wy1;

        const int xi0 = min(max(ix, 0), VW - 2);
        const int yo0 = min(max(iy,     0), VH - 1) * VW;
        const int yo1 = min(max(iy + 1, 0), VH - 1) * VW;
        const int zo0 = min(max(iz,     0), VD - 1) * (VH * VW);
        const int zo1 = min(max(iz + 1, 0), VD - 1) * (VH * VW);

        const int o00 = zo0 + yo0 + xi0, o01 = zo0 + yo1 + xi0;
        const int o10 = zo1 + yo0 + xi0, o11 = zo1 + yo1 + xi0;

        const f2v a00 = *(const uf2v4*)(volc0 + o00);
        const f2v a01 = *(const uf2v4*)(volc0 + o01);
        const f2v a10 = *(const uf2v4*)(volc0 + o10);
        const f2v a11 = *(const uf2v4*)(volc0 + o11);
        const f2v b00 = *(const uf2v4*)(volc1 + o00);
        const f2v b01 = *(const uf2v4*)(volc1 + o01);
        const f2v b10 = *(const uf2v4*)(volc1 + o10);
        const f2v b11 = *(const uf2v4*)(volc1 + o11);

        acc0 += w00 * (wlo * a00.x + whi * a00.y) + w01 * (wlo * a01.x + whi * a01.y)
              + w10 * (wlo * a10.x + whi * a10.y) + w11 * (wlo * a11.x + whi * a11.y);
        acc1 += w00 * (wlo * b00.x + whi * b00.y) + w01 * (wlo * b01.x + whi * b01.y)
              + w10 * (wlo * b10.x + whi * b10.y) + w11 * (wlo * b11.x + whi * b11.y);
    }

    out[c0 * NPIX + p]       = acc0;
    out[(c0 + 1) * NPIX + p] = acc1;
}

extern "C" void kernel_launch(void* const* d_in, const int* in_sizes, int n_in,
                              void* d_out, int out_size, void* d_ws, size_t ws_size,
                              hipStream_t stream) {
    (void)in_sizes; (void)n_in; (void)out_size;
    const float* vol = (const float*)d_in[0]; // (1,32,16,200,200) fp32
    const float* Km  = (const float*)d_in[1]; // (1,3,3) fp32
    const float* Tm  = (const float*)d_in[2]; // (1,4,4) fp32
    float* out = (float*)d_out;               // (1,32,112,200) fp32

    const size_t need = (size_t)NS * NC * sizeof(_Float16); // worst-case volT
    if (ws_size >= need) {
        _Float16* volT = (_Float16*)d_ws;
        vt_transpose_c<<<dim3(NS / 256), dim3(256), 0, stream>>>(vol, volT, Km, Tm);
        vt_sample_c<<<dim3(NPIX / 16), dim3(256), 0, stream>>>(volT, Km, Tm, out);
    } else {
        vt_sample_direct<<<dim3(1400), dim3(256), 0, stream>>>(vol, Km, Tm, out);
    }
}

// Round 5
// 133.379 us; speedup vs baseline: 1.2001x; 1.0057x over previous
//
#include <hip/hip_runtime.h>

// Problem constants (from reference config)
#define FD 56          // depth samples: linspace(2, 58, 56)
#define FH 112         // 900 / 8
#define FW 200         // 1600 / 8
#define VD 16          // volume D
#define VH 200         // volume H
#define VW 200         // volume W
#define NC 32          // channels
#define NPIX (FH * FW)         // 22400
#define NS   (VD * VH * VW)    // 640000 spatial voxels
#define CSTRIDE NS             // floats per channel (channel-major input)

typedef float f2v __attribute__((ext_vector_type(2)));
typedef f2v uf2v4 __attribute__((aligned(4)));   // fallback: 8B vec, 4B-align safe
typedef float f8v __attribute__((ext_vector_type(8)));
typedef _Float16 h8 __attribute__((ext_vector_type(8)));
typedef h8 uh8 __attribute__((aligned(16)));

// Compute fused projection matrix M = e2f @ T @ [[K^-1,0],[0,1]] (12 floats,
// rows = (W,H,D) feature coords). Cheap enough that EVERY thread runs it
// redundantly (~150 VALU) -- removes serial thread-0 + broadcast syncs and
// guarantees bit-identical M in both kernels.
__device__ inline void compute_M(const float* Km, const float* Tm, float* M) {
    float a = Km[0], b = Km[1], c = Km[2];
    float d = Km[3], e = Km[4], f = Km[5];
    float g = Km[6], h = Km[7], i = Km[8];
    float A00 = e * i - f * h, A01 = c * h - b * i, A02 = b * f - c * e;
    float A10 = f * g - d * i, A11 = a * i - c * g, A12 = c * d - a * f;
    float A20 = d * h - e * g, A21 = b * g - a * h, A22 = a * e - b * d;
    float det = a * A00 + b * A10 + c * A20;
    float r = 1.0f / det;
    float Ki[9] = {A00 * r, A01 * r, A02 * r,
                   A10 * r, A11 * r, A12 * r,
                   A20 * r, A21 * r, A22 * r};
    float R[4][4];
    for (int rr = 0; rr < 4; ++rr) {
        for (int cc = 0; cc < 3; ++cc)
            R[rr][cc] = Tm[rr * 4 + 0] * Ki[0 * 3 + cc]
                      + Tm[rr * 4 + 1] * Ki[1 * 3 + cc]
                      + Tm[rr * 4 + 2] * Ki[2 * 3 + cc];
        R[rr][3] = Tm[rr * 4 + 3];
    }
    const float s[3] = {2.5f, 2.5f, 2.5f};
    const float t[3] = {100.0f, 100.0f, 2.5f};
    for (int rr = 0; rr < 3; ++rr)
        for (int cc = 0; cc < 4; ++cc)
            M[rr * 4 + cc] = s[rr] * R[rr][cc] + t[rr] * R[3][cc];
}

// Conservative crop AABB of the sampling frustum: per-depth-slab 4-corner AABB
// (coords affine in image x,y), clipped to the volume, unioned over 56 slabs,
// widened >=1 voxel for trilinear corners + fp slack. HW-verified rounds 1-4.
// Every wave computes it redundantly via shfl (all lanes end with the result,
// no LDS, no syncthreads); deterministic => identical in both kernels.
__device__ inline void compute_crop(const float* m, int& cx0, int& cy0, int& cz0,
                                    int& cw, int& ch, int& cd) {
    const int l = threadIdx.x & 63;
    int bx0 = 0x7fffffff, by0 = 0x7fffffff, bz0 = 0x7fffffff;
    int bx1 = -1, by1 = -1, bz1 = -1;
    if (l < FD) {
        const float gd = 2.0f + (float)l * (56.0f / 55.0f);
        const float HIq[3] = {(float)VW, (float)VH, (float)VD};
        float lo[3], hi[3];
        bool ok = true;
#pragma unroll
        for (int q = 0; q < 3; ++q) {
            const float axx  = m[q * 4 + 0] * gd * 1599.0f;
            const float byy  = m[q * 4 + 1] * gd * 899.0f;
            const float base = m[q * 4 + 2] * gd + m[q * 4 + 3];
            lo[q] = base + fminf(axx, 0.0f) + fminf(byy, 0.0f);
            hi[q] = base + fmaxf(axx, 0.0f) + fmaxf(byy, 0.0f);
            if (!(lo[q] < HIq[q] && hi[q] > -1.0f)) ok = false;  // slab misses volume
        }
        if (ok) {
            const int dmax[3] = {VW - 1, VH - 1, VD - 1};
#pragma unroll
            for (int q = 0; q < 3; ++q) {
                int i0 = (int)floorf(fmaxf(lo[q], -2.0f)) - 1;
                int i1 = (int)floorf(fminf(hi[q], HIq[q] + 1.0f)) + 2;
                i0 = max(i0, 0);
                i1 = min(i1, dmax[q]);
                if (q == 0) { bx0 = i0; bx1 = i1; }
                else if (q == 1) { by0 = i0; by1 = i1; }
                else { bz0 = i0; bz1 = i1; }
            }
        }
    }
#pragma unroll
    for (int s = 1; s < 64; s <<= 1) {
        bx0 = min(bx0, __shfl_xor(bx0, s));
        bx1 = max(bx1, __shfl_xor(bx1, s));
        by0 = min(by0, __shfl_xor(by0, s));
        by1 = max(by1, __shfl_xor(by1, s));
        bz0 = min(bz0, __shfl_xor(bz0, s));
        bz1 = max(bz1, __shfl_xor(bz1, s));
    }
    if (bx1 < bx0 || by1 < by0 || bz1 < bz0) {
        // no slab intersects: all weights zero everywhere; keep a 1-voxel crop
        // so clamped (zero-weight) reads stay in-bounds
        bx0 = by0 = bz0 = 0; bx1 = by1 = bz1 = 0;
    }
    cx0 = bx0; cy0 = by0; cz0 = bz0;
    cw = bx1 - bx0 + 1; ch = by1 - by0 + 1; cd = bz1 - bz0 + 1;
}

// Wedge (camera frustum) half-space block cull -- proven round-0 margins.
// lo/hi: block AABB in absolute volume coords, pre-expanded by caller.
__device__ inline int wedge_skip(const float* M, const float lo[3], const float hi[3]) {
    const float b00 = M[0], b01 = M[1], b02 = M[2],  tx3 = M[3];
    const float b10 = M[4], b11 = M[5], b12 = M[6],  ty3 = M[7];
    const float b20 = M[8], b21 = M[9], b22 = M[10], tz3 = M[11];
    const float C00 = b11 * b22 - b12 * b21;
    const float C01 = b02 * b21 - b01 * b22;
    const float C02 = b01 * b12 - b02 * b11;
    const float C10 = b12 * b20 - b10 * b22;
    const float C11 = b00 * b22 - b02 * b20;
    const float C12 = b02 * b10 - b00 * b12;
    const float C20 = b10 * b21 - b11 * b20;
    const float C21 = b01 * b20 - b00 * b21;
    const float C22 = b00 * b11 - b01 * b10;
    const float det = b00 * C00 + b01 * C10 + b02 * C20;
    if (!(fabsf(det) > 1e-12f)) return 0;
    const float r = 1.0f / det;
    const float ix0 = C00 * r, ix1 = C01 * r, ix2 = C02 * r;
    const float iy0 = C10 * r, iy1 = C11 * r, iy2 = C12 * r;
    const float iz0 = C20 * r, iz1 = C21 * r, iz2 = C22 * r;
    const float cx = -(ix0 * tx3 + ix1 * ty3 + ix2 * tz3);
    const float cy = -(iy0 * tx3 + iy1 * ty3 + iy2 * tz3);
    const float cz = -(iz0 * tx3 + iz1 * ty3 + iz2 * tz3);
    const float SLK = 10.0f;   // generous absolute slack (keep-direction)
    const float gc[6][3] = {
        { iz0,  iz1,  iz2},                                       // w_z - 2
        {-iz0, -iz1, -iz2},                                       // 58 - w_z
        { ix0,  ix1,  ix2},                                       // w_x
        {1599.f*iz0 - ix0, 1599.f*iz1 - ix1, 1599.f*iz2 - ix2},   // 1599 w_z - w_x
        { iy0,  iy1,  iy2},                                       // w_y
        { 899.f*iz0 - iy0,  899.f*iz1 - iy1,  899.f*iz2 - iy2},   // 899 w_z - w_y
    };
    const float gd0[6] = {cz - 2.0f + 0.1f, 58.0f + 0.1f - cz,
                          cx + SLK, 1599.f * cz - cx + SLK,
                          cy + SLK,  899.f * cz - cy + SLK};
    for (int q = 0; q < 6; ++q) {
        float mx = gd0[q];
        for (int j = 0; j < 3; ++j)
            mx += (gc[q][j] > 0.0f) ? gc[q][j] * hi[j] : gc[q][j] * lo[j];
        if (mx < 0.0f) return 1;
    }
    return 0;
}

// ---------------------------------------------------------------------------
// Kernel 1: crop-compacted transpose+downconvert vol (C,S) fp32 -> cropped
// channel-last fp16 volT (CD*CH*CW voxels, 64B per voxel).  Unchanged from the
// verified round-2/3/4 kernel.
// ---------------------------------------------------------------------------
__global__ __launch_bounds__(256)
void vt_transpose_c(const float* __restrict__ vol, _Float16* __restrict__ volT,
                    const float* __restrict__ Km, const float* __restrict__ Tm) {
    __shared__ float tile[256 * 33];
    const int t = threadIdx.x;

    float M[12];
    compute_M(Km, Tm, M);
    int x0, y0, z0, cw, ch, cd;
    compute_crop(M, x0, y0, z0, cw, ch, cd);
    const int chw = ch * cw;
    const int tot = cd * chw;
    const int cb0 = blockIdx.x * 256;
    if (cb0 >= tot) return;                 // uniform: tail block

    // block AABB in absolute volume coords -> wedge cull (uniform decision)
    {
        const int clast = min(cb0 + 255, tot - 1);
        const int ez0 = cb0 / chw, ez1 = clast / chw;
        int ey0 = 0, ey1 = ch - 1;
        if (ez0 == ez1) {
            const int r0 = cb0 - ez0 * chw;
            ey0 = r0 / cw;
            ey1 = (clast - ez0 * chw) / cw;
        }
        const float EXP = 1.25f;
        const float lo[3] = {(float)x0 - EXP, (float)(y0 + ey0) - EXP, (float)(z0 + ez0) - EXP};
        const float hi[3] = {(float)(x0 + cw - 1) + EXP, (float)(y0 + ey1) + EXP, (float)(z0 + ez1) + EXP};
        if (wedge_skip(M, lo, hi)) return;  // uniform: every thread agrees
    }

    const int cidx = cb0 + t;
    const bool live = cidx < tot;
    int lin = 0;
    if (live) {
        const int ez = cidx / chw;
        const int r1 = cidx - ez * chw;
        const int ey = r1 / cw;
        const int ex = r1 - ey * cw;
        lin = (z0 + ez) * (VH * VW) + (y0 + ey) * VW + (x0 + ex);
    }
    if (live) {
#pragma unroll
        for (int c = 0; c < NC; ++c)
            tile[t * 33 + c] = __builtin_nontemporal_load(vol + (size_t)c * CSTRIDE + lin);
    }
    __syncthreads();
    const int rs  = t >> 2;         // row-in-tile 0..63
    const int ch8 = (t & 3) * 8;    // channel octet 0,8,16,24
#pragma unroll
    for (int j = 0; j < 4; ++j) {
        const int sl = j * 64 + rs;
        if (cb0 + sl >= tot) continue;
        const float* r = &tile[sl * 33 + ch8];
        h8 pk = {(_Float16)r[0], (_Float16)r[1], (_Float16)r[2], (_Float16)r[3],
                 (_Float16)r[4], (_Float16)r[5], (_Float16)r[6], (_Float16)r[7]};
        *(h8*)(volT + ((size_t)(cb0 + sl) << 5) + ch8) = pk;  // 16B store, 16B-aligned
    }
}

// ---------------------------------------------------------------------------
// Kernel 2: sampler, wave = 16 pixels x 4 channel-octets (h8 = 16B loads),
// 4-way depth split across the block's 4 waves (round-4 verified structure).
// NEW: balanced XCD column-chunk swizzle.  Blocks land on XCDs round-robin
// (XCD = bid % 8), so chunk = bid & 7 gives each XCD one 25-column azimuth
// wedge of the image: per-XCD gather working set ~12MB/8 + spread ~2-3MB ->
// fits the private 4MB L2 (vs every XCD walking all of volT).  Balanced by
// construction: every chunk spans all image rows, and ray length is a row
// function (rays are not y-clipped inside the crop), so per-chunk work is
// equal -- unlike round-1's row-banding which serialized the horizon rows.
// Fail-safe: if XCD != bid%8, chunks re-mix to today's behavior (neutral).
// ---------------------------------------------------------------------------
__global__ __launch_bounds__(256)
void vt_sample_c(const _Float16* __restrict__ volT,
                 const float* __restrict__ Km,
                 const float* __restrict__ Tm,
                 float* __restrict__ out) {
    __shared__ f8v red[3][64];      // partials from kh=1..3
    float Mv[12];
    compute_M(Km, Tm, Mv);
    int x0, y0, z0, cw, chh, cd;
    compute_crop(Mv, x0, y0, z0, cw, chh, cd);
    const int X0 = x0, X1 = x0 + cw - 1;
    const int Y0 = y0, Y1 = y0 + chh - 1;
    const int Z0 = z0, Z1 = z0 + cd - 1;
    const int CWr = cw, CHWr = chh * cw;

    const int t    = threadIdx.x;
    const int kh   = t >> 6;        // depth-phase 0..3 (wave index)
    const int lane = t & 63;
    const int chq  = lane & 3;      // channel-octet 0..3
    const int pixl = lane >> 2;     // 0..15
    const int c0   = chq * 8;

    // column-chunk pixel mapping: image = 8 chunks x 25 columns x 112 rows
    const int bid   = (int)blockIdx.x;      // 1400 = 8 chunks * 175
    const int chunk = bid & 7;              // -> XCD (if XCD = bid % 8)
    const int i     = (bid >> 3) * 16 + pixl;   // 0..2799 within chunk
    const int py    = i / 25;               // row 0..111
    const int pcx   = i - py * 25;          // column-in-chunk 0..24
    const int px    = chunk * 25 + pcx;     // image column 0..199
    const int p     = py * FW + px;         // pixel index

    const float gx = (float)px * (1599.0f / 199.0f);
    const float gy = (float)py * (899.0f / 111.0f);

    const float m03 = Mv[3], m13 = Mv[7], m23 = Mv[11];
    const float ax = Mv[0] * gx + Mv[1] * gy + Mv[2];
    const float ay = Mv[4] * gx + Mv[5] * gy + Mv[6];
    const float az = Mv[8] * gx + Mv[9] * gy + Mv[10];

    // closed-form hit interval (coords affine in gd), widened 1 step
    float dlo = 2.0f, dhi = 58.0f;
    {
        const float A[3]  = {ax, ay, az};
        const float Bv[3] = {m03, m13, m23};
        const float HI[3] = {(float)VW, (float)VH, (float)VD};
        for (int q = 0; q < 3; ++q) {
            float a = A[q], b = Bv[q], hi = HI[q];
            if (a > 0.0f)      { dlo = fmaxf(dlo, (-1.0f - b) / a); dhi = fminf(dhi, (hi - b) / a); }
            else if (a < 0.0f) { dlo = fmaxf(dlo, (hi - b) / a);    dhi = fminf(dhi, (-1.0f - b) / a); }
            else if (!(b > -1.0f && b < hi)) { dlo = 1e30f; dhi = -1e30f; }
        }
    }
    int klo = (int)ceilf((dlo - 2.0f) * (55.0f / 56.0f));
    int khi = (int)floorf((dhi - 2.0f) * (55.0f / 56.0f));
    klo = max(klo - 1, 0);
    khi = min(khi + 1, FD - 1);

    f8v acc = {0.0f, 0.0f, 0.0f, 0.0f, 0.0f, 0.0f, 0.0f, 0.0f};

#pragma unroll 2
    for (int k = klo + kh; k <= khi; k += 4) {
        const float gd = 2.0f + (float)k * (56.0f / 55.0f);
        const float fx = fmaf(ax, gd, m03);
        const float fy = fmaf(ay, gd, m13);
        const float fz = fmaf(az, gd, m23);

        const bool valid = (fx > -1.0f) && (fx < (float)VW) &&
                           (fy > -1.0f) && (fy < (float)VH) &&
                           (fz > -1.0f) && (fz < (float)VD);
        const float vm = valid ? 1.0f : 0.0f;

        const float xf = floorf(fx), yf = floorf(fy), zf = floorf(fz);
        const float tx = fx - xf, ty = fy - yf, tz = fz - zf;
        const int ix = (int)xf, iy = (int)yf, iz = (int)zf;

        const float wx0 = (ix >= 0)     ? (1.0f - tx) : 0.0f;
        const float wx1 = (ix < VW - 1) ? tx          : 0.0f;
        const float wy0 = (iy >= 0)     ? (1.0f - ty) : 0.0f;
        const float wy1 = (iy < VH - 1) ? ty          : 0.0f;
        const float wz0 = ((iz >= 0)     ? (1.0f - tz) : 0.0f) * vm;
        const float wz1 = ((iz < VD - 1) ? tz          : 0.0f) * vm;

        // clamp into crop box: identity for nonzero-weight corners
        const int xi0 = min(max(ix,     X0), X1) - X0;
        const int xi1 = min(max(ix + 1, X0), X1) - X0;
        const int yo0 = (min(max(iy,     Y0), Y1) - Y0) * CWr;
        const int yo1 = (min(max(iy + 1, Y0), Y1) - Y0) * CWr;
        const int zo0 = (min(max(iz,     Z0), Z1) - Z0) * CHWr;
        const int zo1 = (min(max(iz + 1, Z0), Z1) - Z0) * CHWr;

        const int o000 = ((zo0 + yo0 + xi0) << 5) + c0;
        const int o001 = ((zo0 + yo0 + xi1) << 5) + c0;
        const int o010 = ((zo0 + yo1 + xi0) << 5) + c0;
        const int o011 = ((zo0 + yo1 + xi1) << 5) + c0;
        const int o100 = ((zo1 + yo0 + xi0) << 5) + c0;
        const int o101 = ((zo1 + yo0 + xi1) << 5) + c0;
        const int o110 = ((zo1 + yo1 + xi0) << 5) + c0;
        const int o111 = ((zo1 + yo1 + xi1) << 5) + c0;

        const h8 v000 = *(const uh8*)(volT + o000);
        const h8 v001 = *(const uh8*)(volT + o001);
        const h8 v010 = *(const uh8*)(volT + o010);
        const h8 v011 = *(const uh8*)(volT + o011);
        const h8 v100 = *(const uh8*)(volT + o100);
        const h8 v101 = *(const uh8*)(volT + o101);
        const h8 v110 = *(const uh8*)(volT + o110);
        const h8 v111 = *(const uh8*)(volT + o111);

        const float w000 = wz0 * wy0 * wx0, w001 = wz0 * wy0 * wx1;
        const float w010 = wz0 * wy1 * wx0, w011 = wz0 * wy1 * wx1;
        const float w100 = wz1 * wy0 * wx0, w101 = wz1 * wy0 * wx1;
        const float w110 = wz1 * wy1 * wx0, w111 = wz1 * wy1 * wx1;

#pragma unroll
        for (int j = 0; j < 8; ++j) {
            acc[j] += w000 * (float)v000[j] + w001 * (float)v001[j]
                    + w010 * (float)v010[j] + w011 * (float)v011[j]
                    + w100 * (float)v100[j] + w101 * (float)v101[j]
                    + w110 * (float)v110[j] + w111 * (float)v111[j];
        }
    }

    // cross-wave depth-phase reduction (kh=1..3 -> LDS, kh=0 adds and stores)
    if (kh) red[kh - 1][lane] = acc;
    __syncthreads();
    if (kh == 0) {
        const f8v r0 = red[0][lane];
        const f8v r1 = red[1][lane];
        const f8v r2 = red[2][lane];
#pragma unroll
        for (int j = 0; j < 8; ++j) {
            out[(size_t)(c0 + j) * NPIX + p] = acc[j] + r0[j] + r1[j] + r2[j];
        }
    }
}

// ---------------------------------------------------------------------------
// Fallback (proven Round-6 kernel): channel-major direct sampling, used only
// if the workspace is too small for the transposed volume.
// ---------------------------------------------------------------------------
__global__ __launch_bounds__(256)
void vt_sample_direct(const float* __restrict__ vol,
                      const float* __restrict__ Km,
                      const float* __restrict__ Tm,
                      float* __restrict__ out) {
    __shared__ float sM[12];
    if (threadIdx.x == 0) compute_M(Km, Tm, sM);
    __syncthreads();

    const int cg   = blockIdx.x & 3;
    const int pg   = blockIdx.x >> 2;
    const int lane = threadIdx.x & 63;
    const int wv   = threadIdx.x >> 6;
    const int c0   = (cg * 4 + wv) * 2;
    const int p    = pg * 64 + lane;
    const int py   = p / FW;
    const int px   = p - py * FW;

    const float gx = (float)px * (1599.0f / 199.0f);
    const float gy = (float)py * (899.0f / 111.0f);

    const float m03 = sM[3], m13 = sM[7], m23 = sM[11];
    const float ax = sM[0] * gx + sM[1] * gy + sM[2];
    const float ay = sM[4] * gx + sM[5] * gy + sM[6];
    const float az = sM[8] * gx + sM[9] * gy + sM[10];

    float dlo = 2.0f, dhi = 58.0f;
    {
        const float A[3]  = {ax, ay, az};
        const float Bv[3] = {m03, m13, m23};
        const float HI[3] = {(float)VW, (float)VH, (float)VD};
        for (int q = 0; q < 3; ++q) {
            float a = A[q], b = Bv[q], hi = HI[q];
            if (a > 0.0f)      { dlo = fmaxf(dlo, (-1.0f - b) / a); dhi = fminf(dhi, (hi - b) / a); }
            else if (a < 0.0f) { dlo = fmaxf(dlo, (hi - b) / a);    dhi = fminf(dhi, (-1.0f - b) / a); }
            else if (!(b > -1.0f && b < hi)) { dlo = 1e30f; dhi = -1e30f; }
        }
    }
    int klo = (int)ceilf((dlo - 2.0f) * (55.0f / 56.0f));
    int khi = (int)floorf((dhi - 2.0f) * (55.0f / 56.0f));
    klo = max(klo - 1, 0);
    khi = min(khi + 1, FD - 1);

    const float* __restrict__ volc0 = vol + (size_t)c0 * CSTRIDE;
    const float* __restrict__ volc1 = volc0 + CSTRIDE;
    float acc0 = 0.0f, acc1 = 0.0f;

#pragma unroll 2
    for (int k = klo; k <= khi; ++k) {
        const float gd = 2.0f + (float)k * (56.0f / 55.0f);
        const float fx = fmaf(ax, gd, m03);
        const float fy = fmaf(ay, gd, m13);
        const float fz = fmaf(az, gd, m23);

        const bool valid = (fx > -1.0f) && (fx < (float)VW) &&
                           (fy > -1.0f) && (fy < (float)VH) &&
                           (fz > -1.0f) && (fz < (float)VD);
        const float vm = valid ? 1.0f : 0.0f;

        const float xf = floorf(fx), yf = floorf(fy), zf = floorf(fz);
        const float tx = fx - xf, ty = fy - yf, tz = fz - zf;
        const int ix = (int)xf, iy = (int)yf, iz = (int)zf;

        float wlo = (ix >= 0) ? (1.0f - tx) : tx;
        wlo = (ix >= VW - 1) ? 0.0f : wlo;
        float whi = (ix >= 0) ? tx : 0.0f;
        whi = (ix >= VW - 1) ? (1.0f - tx) : whi;

        const float wy0 = (iy >= 0)     ? (1.0f - ty) : 0.0f;
        const float wy1 = (iy < VH - 1) ? ty          : 0.0f;
        const float wz0 = ((iz >= 0)     ? (1.0f - tz) : 0.0f) * vm;
        const float wz1 = ((iz < VD - 1) ? tz          : 0.0f) * vm;
        const float w00 = wz0 * wy0, w01 = wz0 * wy1;
        const float w10 = wz1 * wy0, w11 = wz1 * wy1;

        const int xi0 = min(max(ix, 0), VW - 2);
        const int yo0 = min(max(iy,     0), VH - 1) * VW;
        const int yo1 = min(max(iy + 1, 0), VH - 1) * VW;
        const int zo0 = min(max(iz,     0), VD - 1) * (VH * VW);
        const int zo1 = min(max(iz + 1, 0), VD - 1) * (VH * VW);

        const int o00 = zo0 + yo0 + xi0, o01 = zo0 + yo1 + xi0;
        const int o10 = zo1 + yo0 + xi0, o11 = zo1 + yo1 + xi0;

        const f2v a00 = *(const uf2v4*)(volc0 + o00);
        const f2v a01 = *(const uf2v4*)(volc0 + o01);
        const f2v a10 = *(const uf2v4*)(volc0 + o10);
        const f2v a11 = *(const uf2v4*)(volc0 + o11);
        const f2v b00 = *(const uf2v4*)(volc1 + o00);
        const f2v b01 = *(const uf2v4*)(volc1 + o01);
        const f2v b10 = *(const uf2v4*)(volc1 + o10);
        const f2v b11 = *(const uf2v4*)(volc1 + o11);

        acc0 += w00 * (wlo * a00.x + whi * a00.y) + w01 * (wlo * a01.x + whi * a01.y)
              + w10 * (wlo * a10.x + whi * a10.y) + w11 * (wlo * a11.x + whi * a11.y);
        acc1 += w00 * (wlo * b00.x + whi * b00.y) + w01 * (wlo * b01.x + whi * b01.y)
              + w10 * (wlo * b10.x + whi * b10.y) + w11 * (wlo * b11.x + whi * b11.y);
    }

    out[c0 * NPIX + p]       = acc0;
    out[(c0 + 1) * NPIX + p] = acc1;
}

extern "C" void kernel_launch(void* const* d_in, const int* in_sizes, int n_in,
                              void* d_out, int out_size, void* d_ws, size_t ws_size,
                              hipStream_t stream) {
    (void)in_sizes; (void)n_in; (void)out_size;
    const float* vol = (const float*)d_in[0]; // (1,32,16,200,200) fp32
    const float* Km  = (const float*)d_in[1]; // (1,3,3) fp32
    const float* Tm  = (const float*)d_in[2]; // (1,4,4) fp32
    float* out = (float*)d_out;               // (1,32,112,200) fp32

    const size_t need = (size_t)NS * NC * sizeof(_Float16); // worst-case volT
    if (ws_size >= need) {
        _Float16* volT = (_Float16*)d_ws;
        vt_transpose_c<<<dim3(NS / 256), dim3(256), 0, stream>>>(vol, volT, Km, Tm);
        vt_sample_c<<<dim3(NPIX / 16), dim3(256), 0, stream>>>(volT, Km, Tm, out);
    } else {
        vt_sample_direct<<<dim3(1400), dim3(256), 0, stream>>>(vol, Km, Tm, out);
    }
}